// Round 9
// baseline (795.715 us; speedup 1.0000x reference)
//
#include <hip/hip_runtime.h>
#include <hip/hip_bf16.h>
#include <cstdint>
#include <cmath>

typedef unsigned int u32;
typedef unsigned long long u64;
typedef float f32x4 __attribute__((ext_vector_type(4)));
typedef __bf16 bf16x8 __attribute__((ext_vector_type(8)));
typedef unsigned short us8 __attribute__((ext_vector_type(8)));
typedef unsigned short us4 __attribute__((ext_vector_type(4)));

#define NN 32768
#define NE 131072
#define FIN 1025
#define HTS 262144
#define HTM (HTS - 1)

// ---------------- workspace layout (byte offsets) ----------------
#define WS_A_D    0ul          // double[NN]
#define WS_B_D    262144ul     // double[NN]
#define WS_EMAX   524288ul     // u32[NN]
#define WS_SSUM   655360ul     // double[NN]
#define WS_EXD    917504ul     // double[NE]
#define WS_CIN    917504ul     // u32[NN]  overlays EXD head (zeroed in apply_sel)
#define WS_KEY    1966080ul    // u64[NE]
#define WS_BEST   3014656ul    // u64[NN]
#define WS_USED   3276800ul    // u32[NN]
#define WS_CUR    3276800ul    // int[NN]  overlays USED (dead after match_fin)
#define WS_ACT0   3407872ul    // int[NE]
#define WS_ACT1   3932160ul    // int[NE]   (zone ends 4456448)
#define WS_BTHI   0ul          // ushort[1024*1024] packed L1 weights (phase B, 0..2097152)
#define WS_BT2    3407872ul    // ushort[1024*512] packed L2 weights (overlays ACT0/1)
#define WS_HT     1966080ul    // u32[HTS] overlays KEY (init in apply_sel, dead after coarse_build)
// readout scratch (phase B, overlays dead KEY tail):
#define WS_RACC1  2097152ul    // float[8*512]   (..2113536)
#define WS_RACC2  2113536ul    // float[8*256]   (..2121728)
// compaction maps: overlay dead HT/KEY tail, AFTER racc2, clear of BTHI (2097152+)
#define WS_CIDX   2129920ul    // int[NN]  node->compact  (..2260992)
#define WS_PERM   2260992ul    // int[NN]  compact->node  (..2392064)
#define WS_BSUM   2392064ul    // int[256] scan block sums (..2393088)
#define WS_BOFF   2393088ul    // int[256] scan block offsets (..2394112, < 3014656 OK)
// persistent:
#define WS_SCORE  4456448ul    // float[NE]
#define WS_CSRA   4456448ul    // int[NE]  overlays SCORE (dead after apply_sel)
#define WS_SEL    4980736ul    // int[NE]
#define WS_CSRC   4980736ul    // float[NE] overlays SEL (dead after apply_sel)
#define WS_CLUST  5505024ul    // int[NN]
#define WS_OTHER  5636096ul    // int[NN]
#define WS_NSC    5767168ul    // float[NN]
#define WS_CEU    5898240ul    // int[NE]
#define WS_CEV    6422528ul    // int[NE]
#define WS_DEG    6946816ul    // u32[NN]
#define WS_OFF    6946816ul    // int[NN]  overlays DEG
#define WS_DIS    7077888ul    // float[NN]
#define WS_PXL    7077888ul    // float[NN] overlays DIS (dis dead after csr_scatter)
#define WS_MISC   7208960ul    // int[64]
#define WS_GMAX   7209216ul    // u32[8*512]
#define WS_GSUM   7225600ul    // float[8*512]
#define WS_GCNT   7241984ul    // float[64]
#define WS_P      7242240ul    // float[NN*512] P0 fp32 (compact rows)
#define WS_PB     74351104ul   // ushort[NN*512] P1 bf16 (=WS_P+67108864, compact rows)
#define WS_H      141459968ul  // Ax/Hb bf16 packed -> H f32[NN*512] (compact rows)

__device__ __forceinline__ u32 enc_f(float f) {
    u32 b = __float_as_uint(f);
    return (b & 0x80000000u) ? ~b : (b | 0x80000000u);
}
__device__ __forceinline__ float dec_f(u32 m) {
    return (m & 0x80000000u) ? __uint_as_float(m ^ 0x80000000u) : __uint_as_float(~m);
}
__device__ __forceinline__ double wave_sum(double v) {
    #pragma unroll
    for (int off = 32; off > 0; off >>= 1) v += __shfl_down(v, off, 64);
    return v;
}
__device__ __forceinline__ unsigned short f2bf(float v) {   // RNE f32->bf16
    u32 b = __float_as_uint(v);
    u32 r = b + 0x7FFFu + ((b >> 16) & 1u);
    return (unsigned short)(r >> 16);
}
__device__ __forceinline__ float bf2f(unsigned short h) {
    return __uint_as_float(((u32)h) << 16);
}
__device__ __forceinline__ bf16x8 ld_frag(const unsigned short* p) {
    union { us8 u; bf16x8 b; } t;
    t.u = *(const us8*)p;
    return t.b;
}
// async global->LDS, 16B/lane; lds base must be wave-uniform
__device__ __forceinline__ void dma16(unsigned short* lds, const unsigned short* g) {
    __builtin_amdgcn_global_load_lds((const __attribute__((address_space(1))) u32*)g,
                                     (__attribute__((address_space(3))) u32*)lds, 16, 0, 0);
}

// ---------------- per-node dots + all phase-A init fused ----------------
__global__ void node_dots(const float* __restrict__ x, const float* __restrict__ pw,
                          double* a_d, double* b_d,
                          u32* emax, double* ssum, u32* deg, int* misc,
                          u32* gmaxb, float* gsum, float* gcnt,
                          u64* best, u32* used, int* clus, int* other, float* nsc) {
    int gid = blockIdx.x * blockDim.x + threadIdx.x;
    if (gid < NN) {
        emax[gid] = 0u; ssum[gid] = 0.0; deg[gid] = 0u;
        best[gid] = ~0ull; used[gid] = 0u;
        clus[gid] = gid; other[gid] = -1; nsc[gid] = 1.0f;
    }
    if (gid < 4096) { gmaxb[gid] = 0u; gsum[gid] = 0.0f; }
    if (gid < 64) { misc[gid] = (gid == 1) ? NE : 0; gcnt[gid] = 0.0f; }

    int wave = gid >> 6;
    int lane = threadIdx.x & 63;
    if (wave >= NN) return;
    const float* xr = x + (size_t)wave * FIN;
    double s0 = 0.0, s1 = 0.0;
    for (int f = lane; f < FIN; f += 64) {
        double xv = (double)xr[f];
        s0 += xv * (double)pw[f];
        s1 += xv * (double)pw[FIN + f];
    }
    s0 = wave_sum(s0); s1 = wave_sum(s1);
    if (lane == 0) { a_d[wave] = s0; b_d[wave] = s1; }
}

// ---------------- edge score pipeline ----------------
__global__ void edge_p1(const int* __restrict__ ei, const double* __restrict__ a_d,
                        const double* __restrict__ b_d, const float* __restrict__ pb,
                        double* e_d, u32* emax) {
    int k = blockIdx.x * 256 + threadIdx.x;
    if (k >= NE) return;
    int u = ei[k], v = ei[NE + k];
    double e = a_d[u] + b_d[v] + (double)pb[0];
    e_d[k] = e;
    atomicMax(&emax[v], enc_f((float)e));
}
__global__ void edge_p2(const int* __restrict__ ei, double* e_d,
                        const u32* __restrict__ emax, double* ssum) {
    int k = blockIdx.x * 256 + threadIdx.x;
    if (k >= NE) return;
    int v = ei[NE + k];
    float mf = dec_f(emax[v]);
    double ex = exp(e_d[k] - (double)mf);
    e_d[k] = ex;
    unsafeAtomicAdd(&ssum[v], ex);
}
__global__ void edge_p3(const int* __restrict__ ei, const double* __restrict__ e_d,
                        const double* __restrict__ ssum, float* score, u64* key,
                        int* sel, int* act0, u64* best) {
    int k = blockIdx.x * 256 + threadIdx.x;
    if (k >= NE) return;
    int u = ei[k], v = ei[NE + k];
    float sc = (float)(e_d[k] / ssum[v] + 0.5);
    score[k] = sc;
    u32 m = enc_f(sc);
    u64 kk = ((u64)(m ^ 0xFFFFFFFFu) << 32) | (u32)k;  // low = high score, tie: low idx
    key[k] = kk;
    sel[k] = 0;
    act0[k] = k;
    atomicMin(&best[u], kk);
    atomicMin(&best[v], kk);
}

// ---------------- flattened dominant-edge peeling rounds ----------------
__global__ void mk_sel(const u64* __restrict__ key, const int* __restrict__ ei,
                       const int* __restrict__ act, const int* __restrict__ cntp,
                       int* ncntp, const u64* __restrict__ best,
                       u32* used, int* sel) {
    int cnt = cntp[0];
    int stride = gridDim.x * blockDim.x;
    int gid = blockIdx.x * blockDim.x + threadIdx.x;
    if (gid == 0) ncntp[0] = 0;
    for (int i = gid; i < cnt; i += stride) {
        int e = act[i];
        u64 k = key[e];
        int a = ei[e], b = ei[NE + e];
        if (best[a] == k && best[b] == k) { sel[e] = 1; used[a] = 1u; used[b] = 1u; }
    }
}
__global__ void mk_compact(const int* __restrict__ ei, const int* __restrict__ act,
                           const int* __restrict__ cntp, int* nxt, int* ncntp,
                           u64* best, const u32* __restrict__ used) {
    int cnt = cntp[0];
    int stride = gridDim.x * blockDim.x;
    for (int i = blockIdx.x * blockDim.x + threadIdx.x; i < cnt; i += stride) {
        int e = act[i];
        int a = ei[e], b = ei[NE + e];
        best[a] = ~0ull; best[b] = ~0ull;
        bool live = !(used[a] | used[b]);
        u64 mask = __ballot(live);
        if (mask) {
            int lane = threadIdx.x & 63;
            int leader = __ffsll((unsigned long long)mask) - 1;
            int base = 0;
            if (lane == leader) base = atomicAdd(ncntp, __popcll(mask));
            base = __shfl(base, leader, 64);
            if (live) nxt[base + __popcll(mask & ((1ull << lane) - 1ull))] = e;
        }
    }
}
__global__ void mk_min(const u64* __restrict__ key, const int* __restrict__ ei,
                       const int* __restrict__ act, const int* __restrict__ cntp,
                       u64* best) {
    int cnt = cntp[0];
    int stride = gridDim.x * blockDim.x;
    for (int i = blockIdx.x * blockDim.x + threadIdx.x; i < cnt; i += stride) {
        int e = act[i];
        u64 k = key[e];
        atomicMin(&best[ei[e]], k);
        atomicMin(&best[ei[NE + e]], k);
    }
}
__global__ void __launch_bounds__(1024) match_fin(
        const u64* __restrict__ key, const int* __restrict__ ei,
        int* sel, u64* best, u32* used,
        int* listA, int* listB, const int* __restrict__ cntp) {
    int tid = threadIdx.x;
    int cnt = cntp[0];
    int* cur = listA; int* nxt = listB;
    __shared__ int s_n;
    for (int round = 0; round < 4096 && cnt > 0; ++round) {
        for (int i = tid; i < cnt; i += 1024) {
            int e = cur[i]; u64 k = key[e];
            atomicMin(&best[ei[e]], k);
            atomicMin(&best[ei[NE + e]], k);
        }
        __syncthreads();
        for (int i = tid; i < cnt; i += 1024) {
            int e = cur[i]; u64 k = key[e];
            int a = ei[e], b = ei[NE + e];
            if (best[a] == k && best[b] == k) { sel[e] = 1; used[a] = 1u; used[b] = 1u; }
        }
        if (tid == 0) s_n = 0;
        __syncthreads();
        for (int i = tid; i < cnt; i += 1024) {
            int e = cur[i];
            int a = ei[e], b = ei[NE + e];
            best[a] = ~0ull; best[b] = ~0ull;
            if (!(used[a] | used[b])) {
                int idx = atomicAdd(&s_n, 1);
                nxt[idx] = e;
            }
        }
        __syncthreads();
        cnt = s_n;
        int* t = cur; cur = nxt; nxt = t;
        __syncthreads();
    }
}

// apply_sel + ht init + cin zero (grid = NE/256; KEY dead here)
__global__ void apply_sel(const int* __restrict__ ei, const int* __restrict__ sel,
                          const float* __restrict__ score,
                          int* cluster, int* other, float* nscore,
                          u32* ht, u32* cin) {
    int e = blockIdx.x * 256 + threadIdx.x;
    ht[e << 1] = 0xFFFFFFFFu;
    ht[(e << 1) + 1] = 0xFFFFFFFFu;
    if (e < NN) cin[e] = 0u;
    if (sel[e] != 1) return;
    int u = ei[e], v = ei[NE + e];
    int rep = min(u, v);
    cluster[u] = rep; cluster[v] = rep;
    if (u != v) other[rep] = u + v - rep;
    nscore[rep] = score[e];
}

// ---------------- coarse graph: dedup (cu,cv) pairs via hash set ----------------
__global__ void coarse_build(const int* __restrict__ ei, const int* __restrict__ cluster,
                             u32* ht, int* misc, int* ce_u, int* ce_v, u32* deg,
                             u32* cin) {
    int e = blockIdx.x * 256 + threadIdx.x;
    if (e >= NE) return;
    int cu = cluster[ei[e]], cv = cluster[ei[NE + e]];
    if (cu == cv) return;
    u32 k = (u32)cu * 32768u + (u32)cv;
    u32 h = ((k * 2654435761u) >> 12) & HTM;
    while (true) {
        u32 old = atomicCAS(&ht[h], 0xFFFFFFFFu, k);
        if (old == 0xFFFFFFFFu) {
            int idx = atomicAdd(&misc[0], 1);
            ce_u[idx] = cu; ce_v[idx] = cv;
            atomicAdd(&deg[cu], 1u);
            atomicAdd(&cin[cv], 1u);
            break;
        }
        if (old == k) break;
        h = (h + 1) & HTM;
    }
}
// dis + readout-scratch zero + gcnt (per-wave ballot reduction; batch sorted)
__global__ void dis_kernel(const u32* __restrict__ deg, float* dis,
                           float* racc1, float* racc2,
                           const int* __restrict__ clus, const int* __restrict__ batch,
                           float* gcnt) {
    int n = blockIdx.x * 256 + threadIdx.x;
    if (n >= NN) return;
    u32 d = deg[n];
    dis[n] = d ? (float)(1.0 / sqrt((double)d)) : 0.0f;
    if (n < 4096) racc1[n] = 0.0f;
    if (n < 2048) racc2[n] = 0.0f;
    bool val = (clus[n] == n);
    int bt = batch[n];
    int lane = threadIdx.x & 63;
    #pragma unroll
    for (int g = 0; g < 8; ++g) {
        u64 m = __ballot(val && bt == g);
        if (m && lane == (__ffsll((unsigned long long)m) - 1))
            unsafeAtomicAdd(&gcnt[g], (float)__popcll(m));
    }
}

// ---------------- multi-block CSR/compaction scan (3 kernels) ----------------
// pass 1: per-256-elem block sums of cin and valid
__global__ void __launch_bounds__(256) scan_part(const u32* __restrict__ cin,
                                                 const int* __restrict__ clus,
                                                 int* __restrict__ bsum) {
    int t = threadIdx.x;
    int i = blockIdx.x * 256 + t;
    int vc = (int)cin[i];
    int vv = (clus[i] == i) ? 1 : 0;
    #pragma unroll
    for (int off = 32; off > 0; off >>= 1) {
        vc += __shfl_down(vc, off, 64);
        vv += __shfl_down(vv, off, 64);
    }
    __shared__ int sc[4], sv[4];
    if ((t & 63) == 0) { sc[t >> 6] = vc; sv[t >> 6] = vv; }
    __syncthreads();
    if (t == 0) {
        bsum[blockIdx.x] = sc[0] + sc[1] + sc[2] + sc[3];
        bsum[128 + blockIdx.x] = sv[0] + sv[1] + sv[2] + sv[3];
    }
}
// pass 2: exclusive scan of the 128 block sums (both arrays); misc[4] = total valid
__global__ void __launch_bounds__(128) scan_mid(const int* __restrict__ bsum,
                                                int* __restrict__ boff, int* misc) {
    __shared__ int s[256];
    int t = threadIdx.x;
    int v0 = bsum[t], v1 = bsum[128 + t];
    s[t] = v0; s[128 + t] = v1;
    __syncthreads();
    for (int d = 1; d < 128; d <<= 1) {
        int a = (t >= d) ? s[t - d] : 0;
        int b = (t >= d) ? s[128 + t - d] : 0;
        __syncthreads();
        if (t >= d) { s[t] += a; s[128 + t] += b; }
        __syncthreads();
    }
    boff[t] = s[t] - v0;            // exclusive
    boff[128 + t] = s[128 + t] - v1;
    if (t == 127) misc[4] = s[255];
}
// pass 3: intra-block exclusive scan (packed (cin<<9)|valid; per-block valid sum
// <= 256 < 512 so the 9-bit field never overflows) + block offset + final writes
__global__ void __launch_bounds__(256) scan_fin(const u32* __restrict__ cin,
                                                const int* __restrict__ clus,
                                                const int* __restrict__ boff,
                                                int* off, int* cur, int* cidx, int* perm) {
    __shared__ int s[256];
    int t = threadIdx.x;
    int i = blockIdx.x * 256 + t;
    int vc = (int)cin[i];
    int vv = (clus[i] == i) ? 1 : 0;
    int p = (vc << 9) | vv;
    s[t] = p;
    __syncthreads();
    for (int d = 1; d < 256; d <<= 1) {
        int a = (t >= d) ? s[t - d] : 0;
        __syncthreads();
        if (t >= d) s[t] += a;
        __syncthreads();
    }
    int ex = s[t] - p;   // exclusive packed prefix
    int o = boff[blockIdx.x] + (ex >> 9);
    off[i] = o; cur[i] = o;
    int c = boff[128 + blockIdx.x] + (ex & 511);
    cidx[i] = c;
    if (vv) perm[c] = i;
}

// csr_a stores COMPACT source row indices (cidx available: scan runs first)
__global__ void csr_scatter(const int* __restrict__ ce_u, const int* __restrict__ ce_v,
                            const float* __restrict__ dis, const int* __restrict__ misc,
                            int* cur, int* csr_a, float* csr_c,
                            const int* __restrict__ cidx) {
    int e = blockIdx.x * 256 + threadIdx.x;
    if (e >= misc[0]) return;
    int a = ce_u[e], b = ce_v[e];
    int pos = atomicAdd(&cur[b], 1);
    csr_a[pos] = cidx[a];
    csr_c[pos] = -dis[a] * dis[b];
}

// ---- packed fragment index: row r, col k -> ushort offset ----
__device__ __forceinline__ size_t pk_idx(int r, int k, int KT) {
    return ((((size_t)(r >> 4) * KT + (k >> 5)) << 6) + (((k >> 3) & 3) << 4) + (r & 15)) << 3;
}

// ---------------- fused: packed Ax gather (COMPACT rows, LDS-staged coalesced) ----------------
__global__ void __launch_bounds__(256) conv_all(
        const float* __restrict__ x, const int* __restrict__ perm,
        const int* __restrict__ misc,
        const int* __restrict__ other, const float* __restrict__ nsc,
        unsigned short* __restrict__ Abf, float* __restrict__ pxl,
        const float* __restrict__ B10, const float* __restrict__ B11,
        unsigned short* __restrict__ Bp1,
        const float* __restrict__ B20, const float* __restrict__ B21,
        unsigned short* __restrict__ Bp2) {
    int bid = blockIdx.x;
    int t = threadIdx.x;
    if (bid < 2048) {   // A-tile gather via coalesced row staging in LDS
        __shared__ unsigned short S[16][1032];   // +8 ushort pad: 2-way max bank alias
        __shared__ int Srow[16], So[16];
        __shared__ float Ss[16];
        int cnt = misc[4];
        int tile = bid;
        if ((tile << 4) >= ((cnt + 127) & ~127)) return;  // beyond padded M': unread
        if (t < 16) {
            int ci = (tile << 4) + t;
            bool val = ci < cnt;
            int row = val ? perm[ci] : -1;
            Srow[t] = row;
            So[t] = val ? other[row] : -1;
            Ss[t] = val ? nsc[row] : 0.0f;
        }
        __syncthreads();
        if (t < 16) {   // pxl (col 1024), 16 scattered scalar loads — tiny
            int row = Srow[t];
            float v = 0.0f;
            if (row >= 0) {
                int o = So[t];
                v = x[(size_t)row * FIN + 1024];
                if (o >= 0) v += x[(size_t)o * FIN + 1024];
                v *= Ss[t];
            }
            pxl[(tile << 4) + t] = v;
        }
        // stage 16 rows: lane t reads cols t, t+256, t+512, t+768 — fully coalesced,
        // all loads independent across k and r (deep MLP)
        for (int r = 0; r < 16; ++r) {
            int row = Srow[r];          // wave-uniform
            int o = So[r];
            float s = Ss[r];
            if (row >= 0) {
                const float* xr = x + (size_t)row * FIN;
                const float* xo = x + (size_t)(o >= 0 ? o : row) * FIN;
                #pragma unroll
                for (int k = 0; k < 4; ++k) {
                    int c = (k << 8) + t;
                    float v = xr[c];
                    if (o >= 0) v += xo[c];
                    S[r][c] = f2bf(v * s);
                }
            } else {
                #pragma unroll
                for (int k = 0; k < 4; ++k) S[r][(k << 8) + t] = 0;
            }
        }
        __syncthreads();
        // pack: 16B LDS reads -> 16B global stores (identical layout/content as before)
        int wave = t >> 6, lane = t & 63;
        int l16 = lane & 15, quad = lane >> 4;
        #pragma unroll
        for (int kt0 = 0; kt0 < 8; ++kt0) {
            int kt = (kt0 << 2) + wave;
            int c0 = (kt << 5) + (quad << 3);
            us8 v = *(const us8*)&S[l16][c0];
            *(us8*)&Abf[((((size_t)tile << 5) + kt) << 9) + ((size_t)lane << 3)] = v;
        }
    } else if (bid < 2560) {   // L1 weight transpose, KT=32
        int j = bid - 2048;
        int n = ((j & 3) << 8) + t;
        int k0 = (j >> 2) << 3;
        unsigned short h[8];
        #pragma unroll
        for (int jj = 0; jj < 8; ++jj) {
            int k = k0 + jj;
            float v = (n < 512) ? B10[(size_t)k * 512 + n] : B11[(size_t)k * 512 + (n - 512)];
            h[jj] = f2bf(v);
        }
        *(us8*)&Bp1[pk_idx(n, k0, 32)] = *(const us8*)h;
    } else {                   // L2 weight transpose, KT=16
        int j = bid - 2560;
        int n = ((j & 3) << 8) + t;
        int k0 = (j >> 2) << 3;
        unsigned short h[8];
        #pragma unroll
        for (int jj = 0; jj < 8; ++jj) {
            int k = k0 + jj;
            float v = (n < 512) ? B20[(size_t)k * 512 + n] : B21[(size_t)k * 512 + (n - 512)];
            h[jj] = f2bf(v);
        }
        *(us8*)&Bp2[pk_idx(n, k0, 16)] = *(const us8*)h;
    }
}

// ---------------- packed-fragment bf16 MFMA GEMM with LDS DMA double-buffer ----------------
// Transposed-output form: acc[ni][mi] = mfma(bf, af) computes D^T fragments, so each
// lane holds 4 CONSECUTIVE N-columns at a fixed M-row -> direct float4/us4 stores.
// __launch_bounds__(256,5): 5 blocks/CU (5 x 32KB = 160KB LDS exactly) -> all ~1128
// active blocks co-resident in ONE round (4/CU gave 1024 slots -> 2 rounds, 2nd 10% full).
template <bool R1>
__global__ void __launch_bounds__(256, 5) gemm_pk(
        const unsigned short* __restrict__ Ap, const unsigned short* __restrict__ Bp,
        float* __restrict__ P, unsigned short* __restrict__ Pb, int KT,
        const float* __restrict__ pxl, const float* __restrict__ w0,
        const float* __restrict__ w1, const int* __restrict__ msc) {
    __shared__ unsigned short L[2][8192];
    int tid = threadIdx.x;
    int bid = blockIdx.x;
    int bn = (bid & 7) << 7;
    int bm = (bid >> 3) << 7;                    // dead blocks = contiguous grid tail
    if (bm >= ((msc[4] + 127) & ~127)) return;   // zero-row block: output never read
    int wave = tid >> 6, lane = tid & 63, quad = lane >> 4, l16 = lane & 15;
    int moff = (wave >> 1) << 6, noff = (wave & 1) << 6;
    f32x4 acc[4][4];   // [ni][mi] — transposed-output fragments
    #pragma unroll
    for (int i = 0; i < 4; ++i)
        #pragma unroll
        for (int j = 0; j < 4; ++j) acc[i][j] = (f32x4){0.f, 0.f, 0.f, 0.f};

    const unsigned short* src[4];
    unsigned short* dst[4];
    #pragma unroll
    for (int q = 0; q < 4; ++q) {
        int f = (wave << 2) + q;
        int tg = (f < 8) ? ((bm >> 4) + f) : ((bn >> 4) + (f - 8));
        src[q] = ((f < 8) ? Ap : Bp) + (((size_t)tg * KT) << 9) + ((size_t)lane << 3);
        dst[q] = &L[0][(size_t)f << 9];
    }
    const unsigned short* ra = &L[0][(size_t)(wave >> 1) << 11];
    const unsigned short* rb = &L[0][4096 + ((size_t)(wave & 1) << 11)];

    #pragma unroll
    for (int q = 0; q < 4; ++q) dma16(dst[q], src[q]);
    __syncthreads();

    int cur = 0;
    for (int kt = 0; kt < KT; ++kt) {
        if (kt + 1 < KT) {
            int nb = (cur ^ 1) * 8192;
            size_t go = ((size_t)(kt + 1)) << 9;
            #pragma unroll
            for (int q = 0; q < 4; ++q) dma16(dst[q] + nb, src[q] + go);
        }
        const unsigned short* la = ra + cur * 8192;
        const unsigned short* lb = rb + cur * 8192;
        bf16x8 af[4], bf[4];
        #pragma unroll
        for (int i = 0; i < 4; ++i) {
            af[i] = ld_frag(la + ((size_t)i << 9) + (lane << 3));
            bf[i] = ld_frag(lb + ((size_t)i << 9) + (lane << 3));
        }
        #pragma unroll
        for (int ni = 0; ni < 4; ++ni)
            #pragma unroll
            for (int mi = 0; mi < 4; ++mi)
                acc[ni][mi] = __builtin_amdgcn_mfma_f32_16x16x32_bf16(bf[ni], af[mi], acc[ni][mi], 0, 0, 0);
        __syncthreads();
        cur ^= 1;
    }
    // ---- epilogue: D^T fragment: n = bn+noff+ni*16+quad*4+r2, m = bm+moff+mi*16+l16.
    // 4 consecutive n per lane -> float4 (P) / us4 (Pb) stores; rank-1 weight is a
    // contiguous float4 load. Blocks are pure-P (bn<512) or pure-Pb (bn multiple of 128).
    #pragma unroll
    for (int mi = 0; mi < 4; ++mi) {
        int m = bm + moff + (mi << 4) + l16;
        float pm = 0.0f;
        if (R1) pm = pxl[m];
        #pragma unroll
        for (int ni = 0; ni < 4; ++ni) {
            int n0 = bn + noff + (ni << 4) + (quad << 2);
            float v0 = acc[ni][mi][0], v1 = acc[ni][mi][1];
            float v2 = acc[ni][mi][2], v3 = acc[ni][mi][3];
            if (bn < 512) {
                if (R1) {
                    float4 wv = *(const float4*)&w0[524288 + n0];
                    v0 += pm * wv.x; v1 += pm * wv.y; v2 += pm * wv.z; v3 += pm * wv.w;
                }
                *(float4*)&P[(size_t)m * 512 + n0] = make_float4(v0, v1, v2, v3);
            } else {
                if (R1) {
                    float4 wv = *(const float4*)&w1[524288 + n0 - 512];
                    v0 += pm * wv.x; v1 += pm * wv.y; v2 += pm * wv.z; v3 += pm * wv.w;
                }
                unsigned short h[4] = {f2bf(v0), f2bf(v1), f2bf(v2), f2bf(v3)};
                *(us4*)&Pb[(size_t)m * 512 + (n0 - 512)] = *(const us4*)h;
            }
        }
    }
}

// ---------------- fused gather + BN + ReLU: one wave per COMPACT destination row ----------------
template <bool BF16OUT>
__global__ void __launch_bounds__(256) cheb_fuse(
        const float* __restrict__ P, const unsigned short* __restrict__ Pb,
        const int* __restrict__ off,
        const int* __restrict__ csr_a, const float* __restrict__ csr_c,
        const int* __restrict__ misc, const float* __restrict__ bias,
        const float* __restrict__ bn, float* __restrict__ Hf,
        unsigned short* __restrict__ Hb, const int* __restrict__ perm) {
    int b = (blockIdx.x * 256 + threadIdx.x) >> 6;
    int lane = threadIdx.x & 63;
    if (b >= misc[4]) return;
    int r = perm[b];
    int s = off[r];
    int e = (r < NN - 1) ? off[r + 1] : misc[0];
    int c0 = lane << 3;
    float a0[4], a1[4];
    {
        float4 t0 = *(const float4*)&P[(size_t)b * 512 + c0];
        float4 t1 = *(const float4*)&P[(size_t)b * 512 + c0 + 4];
        a0[0] = t0.x; a0[1] = t0.y; a0[2] = t0.z; a0[3] = t0.w;
        a1[0] = t1.x; a1[1] = t1.y; a1[2] = t1.z; a1[3] = t1.w;
    }
    for (int j = s; j < e; ++j) {
        int a = csr_a[j];          // already a compact row index
        float cf = csr_c[j];
        us8 raw = *(const us8*)&Pb[(size_t)a * 512 + c0];
        a0[0] = fmaf(cf, bf2f(raw[0]), a0[0]); a0[1] = fmaf(cf, bf2f(raw[1]), a0[1]);
        a0[2] = fmaf(cf, bf2f(raw[2]), a0[2]); a0[3] = fmaf(cf, bf2f(raw[3]), a0[3]);
        a1[0] = fmaf(cf, bf2f(raw[4]), a1[0]); a1[1] = fmaf(cf, bf2f(raw[5]), a1[1]);
        a1[2] = fmaf(cf, bf2f(raw[6]), a1[2]); a1[3] = fmaf(cf, bf2f(raw[7]), a1[3]);
    }
    float o[8];
    #pragma unroll
    for (int i = 0; i < 8; ++i) {
        int j = c0 + i;
        float acc = (i < 4) ? a0[i] : a1[i - 4];
        float ga = bn[j], be = bn[512 + j], mn = bn[1024 + j], vr = bn[1536 + j];
        float sc = (float)(1.0 / sqrt((double)vr + 1e-5));
        float v = (acc + bias[j] - mn) * sc * ga + be;
        o[i] = v > 0.0f ? v : 0.0f;
    }
    if (BF16OUT) {
        unsigned short h[8];
        #pragma unroll
        for (int i = 0; i < 8; ++i) h[i] = f2bf(o[i]);
        *(us8*)&Hb[pk_idx(b, c0, 16)] = *(const us8*)h;   // packed for layer-2 GEMM
    } else {
        *(float4*)&Hf[(size_t)b * 512 + c0] = make_float4(o[0], o[1], o[2], o[3]);
        *(float4*)&Hf[(size_t)b * 512 + c0 + 4] = make_float4(o[4], o[5], o[6], o[7]);
    }
}

// ---------------- global max+mean pool over valid nodes per graph ----------------
// H rows are compact; gather via cidx[n] (monotone over n -> stays coalesced).
// 2048 blocks x 16 nodes: 8 blocks/CU (vs 2 at 64-node chunks) — latency-bound fix.
__global__ void __launch_bounds__(256) pool_kernel(
        const float* __restrict__ H, const int* __restrict__ cluster,
        const int* __restrict__ batch, u32* gmaxb, float* gsum,
        const int* __restrict__ cidx) {
    int t = threadIdx.x;
    int n0 = blockIdx.x * 16;
    float m0 = 0.0f, m1 = 0.0f, s0 = 0.0f, s1 = 0.0f;
    int cur = batch[n0];
    for (int i = 0; i < 16; ++i) {
        int n = n0 + i;
        int bt = batch[n];
        if (bt != cur) {
            atomicMax(&gmaxb[cur * 512 + t], __float_as_uint(m0));
            atomicMax(&gmaxb[cur * 512 + t + 256], __float_as_uint(m1));
            unsafeAtomicAdd(&gsum[cur * 512 + t], s0);
            unsafeAtomicAdd(&gsum[cur * 512 + t + 256], s1);
            m0 = m1 = s0 = s1 = 0.0f; cur = bt;
        }
        if (cluster[n] == n) {
            size_t ci = (size_t)cidx[n];
            float h0 = H[ci * 512 + t];
            float h1 = H[ci * 512 + t + 256];
            m0 = fmaxf(m0, h0); m1 = fmaxf(m1, h1);
            s0 += h0; s1 += h1;
        }
    }
    atomicMax(&gmaxb[cur * 512 + t], __float_as_uint(m0));
    atomicMax(&gmaxb[cur * 512 + t + 256], __float_as_uint(m1));
    unsafeAtomicAdd(&gsum[cur * 512 + t], s0);
    unsafeAtomicAdd(&gsum[cur * 512 + t + 256], s1);
}

// ---------------- parallel readout MLP (3 kernels) ----------------
__global__ void __launch_bounds__(512) ro1(
        const u32* __restrict__ gmaxb, const float* __restrict__ gsum,
        const float* __restrict__ gcnt, const float* __restrict__ l1w,
        float* __restrict__ racc1) {
    int o = threadIdx.x;
    int k0 = blockIdx.x << 4;
    float acc[8] = {0, 0, 0, 0, 0, 0, 0, 0};
    float inv[8];
    #pragma unroll
    for (int b = 0; b < 8; ++b) inv[b] = 1.0f / fmaxf(gcnt[b], 1.0f);
    for (int kk = 0; kk < 16; ++kk) {
        int k = k0 + kk;
        float w = l1w[(size_t)k * 512 + o];
        #pragma unroll
        for (int b = 0; b < 8; ++b) {
            float g = (k < 512) ? __uint_as_float(gmaxb[b * 512 + k])
                                : gsum[b * 512 + (k - 512)] * inv[b];
            acc[b] = fmaf(g, w, acc[b]);
        }
    }
    #pragma unroll
    for (int b = 0; b < 8; ++b) unsafeAtomicAdd(&racc1[b * 512 + o], acc[b]);
}
// ro3: layer-2 partials with ro2's BN inlined (recomputed per k-slice)
__global__ void __launch_bounds__(256) ro3(
        const float* __restrict__ racc1, const float* __restrict__ l1b,
        const float* __restrict__ bn3, const float* __restrict__ l2w,
        float* __restrict__ racc2) {
    int o = threadIdx.x;
    int k0 = blockIdx.x << 4;
    float acc[8] = {0, 0, 0, 0, 0, 0, 0, 0};
    for (int kk = 0; kk < 16; ++kk) {
        int k = k0 + kk;
        float ga = bn3[k], be = bn3[512 + k], mn = bn3[1024 + k], vr = bn3[1536 + k];
        float sc = (float)(1.0 / sqrt((double)vr + 1e-5));
        float bi = l1b[k];
        float w = l2w[(size_t)k * 256 + o];
        #pragma unroll
        for (int b = 0; b < 8; ++b) {
            float g1 = (racc1[b * 512 + k] + bi - mn) * sc * ga + be;
            g1 = g1 > 0.0f ? g1 : 0.0f;
            acc[b] = fmaf(g1, w, acc[b]);
        }
    }
    #pragma unroll
    for (int b = 0; b < 8; ++b) unsafeAtomicAdd(&racc2[b * 256 + o], acc[b]);
}
__global__ void __launch_bounds__(256) ro4(
        const float* __restrict__ racc2, const float* __restrict__ l2b,
        const float* __restrict__ bn4, const float* __restrict__ l3w,
        const float* __restrict__ l3b, float* __restrict__ out) {
    __shared__ float G2[8 * 256];
    int o = threadIdx.x;
    {
        float ga = bn4[o], be = bn4[256 + o], mn = bn4[512 + o], vr = bn4[768 + o];
        float sc = (float)(1.0 / sqrt((double)vr + 1e-5));
        float bi = l2b[o];
        #pragma unroll
        for (int b = 0; b < 8; ++b) {
            float v = (racc2[b * 256 + o] + bi - mn) * sc * ga + be;
            v = v > 0.0f ? v : 0.0f;
            G2[b * 256 + o] = v;
            out[32 + b * 256 + o] = v;
        }
    }
    __syncthreads();
    if (o < 8) {
        int b = o;
        float r[4];
        #pragma unroll
        for (int c = 0; c < 4; ++c) {
            float acc = l3b[c];
            for (int k = 0; k < 256; ++k) acc += G2[b * 256 + k] * l3w[k * 4 + c];
            r[c] = acc > 0.0f ? acc : 0.0f;
        }
        float mx = fmaxf(fmaxf(r[0], r[1]), fmaxf(r[2], r[3]));
        float s = 0.0f;
        #pragma unroll
        for (int c = 0; c < 4; ++c) s += expf(r[c] - mx);
        float lse = mx + logf(s);
        #pragma unroll
        for (int c = 0; c < 4; ++c) out[b * 4 + c] = r[c] - lse;
    }
}

extern "C" void kernel_launch(void* const* d_in, const int* in_sizes, int n_in,
                              void* d_out, int out_size, void* d_ws, size_t ws_size,
                              hipStream_t stream) {
    const float* x      = (const float*)d_in[0];
    const int*   ei     = (const int*)d_in[1];
    const int*   batch  = (const int*)d_in[2];
    const float* pool_w = (const float*)d_in[3];
    const float* pool_b = (const float*)d_in[4];
    const float* c1_w0  = (const float*)d_in[5];
    const float* c1_w1  = (const float*)d_in[6];
    const float* c1_b   = (const float*)d_in[7];
    const float* c2_w0  = (const float*)d_in[8];
    const float* c2_w1  = (const float*)d_in[9];
    const float* c2_b   = (const float*)d_in[10];
    const float* bn1    = (const float*)d_in[11];
    const float* bn2    = (const float*)d_in[12];
    const float* bn3    = (const float*)d_in[13];
    const float* bn4    = (const float*)d_in[14];
    const float* l1w    = (const float*)d_in[15];
    const float* l1b    = (const float*)d_in[16];
    const float* l2w    = (const float*)d_in[17];
    const float* l2b    = (const float*)d_in[18];
    const float* l3w    = (const float*)d_in[19];
    const float* l3b    = (const float*)d_in[20];
    float* out = (float*)d_out;
    char* ws = (char*)d_ws;

    double* a_d   = (double*)(ws + WS_A_D);
    double* b_d   = (double*)(ws + WS_B_D);
    u32*    emax  = (u32*)(ws + WS_EMAX);
    double* ssum  = (double*)(ws + WS_SSUM);
    double* exd   = (double*)(ws + WS_EXD);
    u32*    cin   = (u32*)(ws + WS_CIN);
    int*    cidxp = (int*)(ws + WS_CIDX);
    int*    permp = (int*)(ws + WS_PERM);
    int*    bsum  = (int*)(ws + WS_BSUM);
    int*    boffp = (int*)(ws + WS_BOFF);
    u64*    key   = (u64*)(ws + WS_KEY);
    u64*    best  = (u64*)(ws + WS_BEST);
    u32*    used  = (u32*)(ws + WS_USED);
    int*    curp  = (int*)(ws + WS_CUR);
    int*    act0  = (int*)(ws + WS_ACT0);
    int*    act1  = (int*)(ws + WS_ACT1);
    unsigned short* bthi = (unsigned short*)(ws + WS_BTHI);
    unsigned short* bt2  = (unsigned short*)(ws + WS_BT2);
    float*  pxl   = (float*)(ws + WS_PXL);
    u32*    ht    = (u32*)(ws + WS_HT);
    float*  racc1 = (float*)(ws + WS_RACC1);
    float*  racc2 = (float*)(ws + WS_RACC2);
    float*  score = (float*)(ws + WS_SCORE);
    int*    csr_a = (int*)(ws + WS_CSRA);
    int*    sel   = (int*)(ws + WS_SEL);
    float*  csr_c = (float*)(ws + WS_CSRC);
    int*    clus  = (int*)(ws + WS_CLUST);
    int*    other = (int*)(ws + WS_OTHER);
    float*  nsc   = (float*)(ws + WS_NSC);
    int*    ce_u  = (int*)(ws + WS_CEU);
    int*    ce_v  = (int*)(ws + WS_CEV);
    u32*    deg   = (u32*)(ws + WS_DEG);
    int*    off   = (int*)(ws + WS_OFF);
    float*  dis   = (float*)(ws + WS_DIS);
    int*    misc  = (int*)(ws + WS_MISC);
    u32*    gmaxb = (u32*)(ws + WS_GMAX);
    float*  gsum  = (float*)(ws + WS_GSUM);
    float*  gcnt  = (float*)(ws + WS_GCNT);
    float*  P     = (float*)(ws + WS_P);
    unsigned short* Pb = (unsigned short*)(ws + WS_PB);
    unsigned short* ax = (unsigned short*)(ws + WS_H);   // packed Ax bf16 (gemm1 A)
    unsigned short* hb = (unsigned short*)(ws + WS_H);   // packed Hb bf16 (gemm2 A)
    float*  H     = (float*)(ws + WS_H);                 // final H fp32

    // ---- phase A: scores, matching, coarse graph ----
    node_dots<<<NN / 4, 256, 0, stream>>>(x, pool_w, a_d, b_d,
                                          emax, ssum, deg, misc, gmaxb, gsum, gcnt,
                                          best, used, clus, other, nsc);
    edge_p1<<<NE / 256, 256, 0, stream>>>(ei, a_d, b_d, pool_b, exd, emax);
    edge_p2<<<NE / 256, 256, 0, stream>>>(ei, exd, emax, ssum);
    edge_p3<<<NE / 256, 256, 0, stream>>>(ei, exd, ssum, score, key, sel, act0, best);

    {
        static const int gr[9] = {512, 512, 256, 128, 64, 32, 16, 8, 8};
        int* acts[2] = {act0, act1};
        for (int r = 0; r < 8; ++r) {
            int c = r & 1, n = 1 - c;
            mk_sel<<<gr[r], 256, 0, stream>>>(key, ei, acts[c], &misc[1 + c],
                                              &misc[1 + n], best, used, sel);
            mk_compact<<<gr[r], 256, 0, stream>>>(ei, acts[c], &misc[1 + c],
                                                  acts[n], &misc[1 + n], best, used);
            mk_min<<<gr[r + 1], 256, 0, stream>>>(key, ei, acts[n], &misc[1 + n], best);
        }
        match_fin<<<1, 1024, 0, stream>>>(key, ei, sel, best, used,
                                          act0, act1, &misc[1]);
    }

    apply_sel<<<NE / 256, 256, 0, stream>>>(ei, sel, score, clus, other, nsc, ht, cin);
    coarse_build<<<NE / 256, 256, 0, stream>>>(ei, clus, ht, misc, ce_u, ce_v, deg, cin);
    dis_kernel<<<NN / 256, 256, 0, stream>>>(deg, dis, racc1, racc2, clus, batch, gcnt);
    scan_part<<<128, 256, 0, stream>>>(cin, clus, bsum);
    scan_mid<<<1, 128, 0, stream>>>(bsum, boffp, misc);
    scan_fin<<<128, 256, 0, stream>>>(cin, clus, boffp, off, curp, cidxp, permp);
    csr_scatter<<<NE / 256, 256, 0, stream>>>(ce_u, ce_v, dis, misc, curp, csr_a, csr_c,
                                              cidxp);

    // ---- phase B: ChebConv layers on COMPACT rows (misc[4] ~ 0.55*NN survive) ----
    conv_all<<<2816, 256, 0, stream>>>(x, permp, misc, other, nsc, ax, pxl,
                                       c1_w0, c1_w1, bthi, c2_w0, c2_w1, bt2);
    gemm_pk<true><<<2048, 256, 0, stream>>>(ax, bthi, P, Pb, 32, pxl, c1_w0, c1_w1, misc);
    cheb_fuse<true><<<NN / 4, 256, 0, stream>>>(P, Pb, off, csr_a, csr_c, misc, c1_b, bn1,
                                                nullptr, hb, permp);

    gemm_pk<false><<<2048, 256, 0, stream>>>(hb, bt2, P, Pb, 16, nullptr, nullptr, nullptr,
                                             misc);
    cheb_fuse<false><<<NN / 4, 256, 0, stream>>>(P, Pb, off, csr_a, csr_c, misc, c2_b, bn2,
                                                 H, nullptr, permp);

    pool_kernel<<<NN / 16, 256, 0, stream>>>(H, clus, batch, gmaxb, gsum, cidxp);

    // ---- parallel readout ----
    ro1<<<64, 512, 0, stream>>>(gmaxb, gsum, gcnt, l1w, racc1);
    ro3<<<32, 256, 0, stream>>>(racc1, l1b, bn3, l2w, racc2);
    ro4<<<1, 256, 0, stream>>>(racc2, l2b, bn4, l3w, l3b, out);
}

// Round 10
// 719.465 us; speedup vs baseline: 1.1060x; 1.1060x over previous
//
#include <hip/hip_runtime.h>
#include <hip/hip_bf16.h>
#include <cstdint>
#include <cmath>

typedef unsigned int u32;
typedef unsigned long long u64;
typedef float f32x4 __attribute__((ext_vector_type(4)));
typedef __bf16 bf16x8 __attribute__((ext_vector_type(8)));
typedef unsigned short us8 __attribute__((ext_vector_type(8)));
typedef unsigned short us4 __attribute__((ext_vector_type(4)));

#define NN 32768
#define NE 131072
#define FIN 1025
#define HTS 262144
#define HTM (HTS - 1)

// ---------------- workspace layout (byte offsets) ----------------
#define WS_A_D    0ul          // double[NN]
#define WS_B_D    262144ul     // double[NN]
#define WS_EMAX   524288ul     // u32[NN]
#define WS_SSUM   655360ul     // double[NN]
#define WS_EXD    917504ul     // double[NE]
#define WS_CIN    917504ul     // u32[NN]  overlays EXD head (zeroed in apply_sel)
#define WS_KEY    1966080ul    // u64[NE]
#define WS_BEST   3014656ul    // u64[NN]
#define WS_USED   3276800ul    // u32[NN]
#define WS_CUR    3276800ul    // int[NN]  overlays USED (dead after match_fin)
#define WS_ACT0   3407872ul    // int[NE]
#define WS_ACT1   3932160ul    // int[NE]   (zone ends 4456448)
#define WS_BTHI   0ul          // ushort[1024*1024] packed L1 weights (phase B, 0..2097152)
#define WS_BT2    3407872ul    // ushort[1024*512] packed L2 weights (overlays ACT0/1)
#define WS_HT     1966080ul    // u32[HTS] overlays KEY (init in apply_sel, dead after coarse_build)
// readout scratch (phase B, overlays dead KEY tail):
#define WS_RACC1  2097152ul    // float[8*512]   (..2113536)
#define WS_RACC2  2113536ul    // float[8*256]   (..2121728)
// compaction maps: overlay dead HT/KEY tail, AFTER racc2, clear of BTHI (2097152+)
#define WS_CIDX   2129920ul    // int[NN]  node->compact  (..2260992)
#define WS_PERM   2260992ul    // int[NN]  compact->node  (..2392064)
#define WS_BSUM   2392064ul    // int[256] scan block sums (..2393088)
#define WS_BOFF   2393088ul    // int[256] scan block offsets (..2394112, < 3014656 OK)
// persistent:
#define WS_SCORE  4456448ul    // float[NE]
#define WS_CSRA   4456448ul    // int[NE]  overlays SCORE (dead after apply_sel)
#define WS_SEL    4980736ul    // int[NE]
#define WS_CSRC   4980736ul    // float[NE] overlays SEL (dead after apply_sel)
#define WS_CLUST  5505024ul    // int[NN]
#define WS_OTHER  5636096ul    // int[NN]
#define WS_NSC    5767168ul    // float[NN]
#define WS_CEU    5898240ul    // int[NE]
#define WS_CEV    6422528ul    // int[NE]
#define WS_DEG    6946816ul    // u32[NN]
#define WS_OFF    6946816ul    // int[NN]  overlays DEG
#define WS_DIS    7077888ul    // float[NN]
#define WS_PXL    7077888ul    // float[NN] overlays DIS (dis dead after csr_scatter)
#define WS_MISC   7208960ul    // int[64]
#define WS_GMAX   7209216ul    // u32[8*512]
#define WS_GSUM   7225600ul    // float[8*512]
#define WS_GCNT   7241984ul    // float[64]
#define WS_P      7242240ul    // float[NN*512] P0 fp32 (compact rows)
#define WS_PB     74351104ul   // ushort[NN*512] P1 bf16 (=WS_P+67108864, compact rows)
#define WS_H      141459968ul  // Ax/Hb bf16 packed -> H f32[NN*512] (compact rows)

__device__ __forceinline__ u32 enc_f(float f) {
    u32 b = __float_as_uint(f);
    return (b & 0x80000000u) ? ~b : (b | 0x80000000u);
}
__device__ __forceinline__ float dec_f(u32 m) {
    return (m & 0x80000000u) ? __uint_as_float(m ^ 0x80000000u) : __uint_as_float(~m);
}
__device__ __forceinline__ double wave_sum(double v) {
    #pragma unroll
    for (int off = 32; off > 0; off >>= 1) v += __shfl_down(v, off, 64);
    return v;
}
__device__ __forceinline__ unsigned short f2bf(float v) {   // RNE f32->bf16
    u32 b = __float_as_uint(v);
    u32 r = b + 0x7FFFu + ((b >> 16) & 1u);
    return (unsigned short)(r >> 16);
}
__device__ __forceinline__ float bf2f(unsigned short h) {
    return __uint_as_float(((u32)h) << 16);
}
__device__ __forceinline__ bf16x8 ld_frag(const unsigned short* p) {
    union { us8 u; bf16x8 b; } t;
    t.u = *(const us8*)p;
    return t.b;
}
// async global->LDS, 16B/lane; lds base must be wave-uniform
__device__ __forceinline__ void dma16(unsigned short* lds, const unsigned short* g) {
    __builtin_amdgcn_global_load_lds((const __attribute__((address_space(1))) u32*)g,
                                     (__attribute__((address_space(3))) u32*)lds, 16, 0, 0);
}

// ---------------- per-node dots + all phase-A init fused ----------------
__global__ void node_dots(const float* __restrict__ x, const float* __restrict__ pw,
                          double* a_d, double* b_d,
                          u32* emax, double* ssum, u32* deg, int* misc,
                          u32* gmaxb, float* gsum, float* gcnt,
                          u64* best, u32* used, int* clus, int* other, float* nsc) {
    int gid = blockIdx.x * blockDim.x + threadIdx.x;
    if (gid < NN) {
        emax[gid] = 0u; ssum[gid] = 0.0; deg[gid] = 0u;
        best[gid] = ~0ull; used[gid] = 0u;
        clus[gid] = gid; other[gid] = -1; nsc[gid] = 1.0f;
    }
    if (gid < 4096) { gmaxb[gid] = 0u; gsum[gid] = 0.0f; }
    if (gid < 64) { misc[gid] = (gid == 1) ? NE : 0; gcnt[gid] = 0.0f; }

    int wave = gid >> 6;
    int lane = threadIdx.x & 63;
    if (wave >= NN) return;
    const float* xr = x + (size_t)wave * FIN;
    double s0 = 0.0, s1 = 0.0;
    for (int f = lane; f < FIN; f += 64) {
        double xv = (double)xr[f];
        s0 += xv * (double)pw[f];
        s1 += xv * (double)pw[FIN + f];
    }
    s0 = wave_sum(s0); s1 = wave_sum(s1);
    if (lane == 0) { a_d[wave] = s0; b_d[wave] = s1; }
}

// ---------------- edge score pipeline ----------------
__global__ void edge_p1(const int* __restrict__ ei, const double* __restrict__ a_d,
                        const double* __restrict__ b_d, const float* __restrict__ pb,
                        double* e_d, u32* emax) {
    int k = blockIdx.x * 256 + threadIdx.x;
    if (k >= NE) return;
    int u = ei[k], v = ei[NE + k];
    double e = a_d[u] + b_d[v] + (double)pb[0];
    e_d[k] = e;
    atomicMax(&emax[v], enc_f((float)e));
}
__global__ void edge_p2(const int* __restrict__ ei, double* e_d,
                        const u32* __restrict__ emax, double* ssum) {
    int k = blockIdx.x * 256 + threadIdx.x;
    if (k >= NE) return;
    int v = ei[NE + k];
    float mf = dec_f(emax[v]);
    double ex = exp(e_d[k] - (double)mf);
    e_d[k] = ex;
    unsafeAtomicAdd(&ssum[v], ex);
}
__global__ void edge_p3(const int* __restrict__ ei, const double* __restrict__ e_d,
                        const double* __restrict__ ssum, float* score, u64* key,
                        int* sel, int* act0, u64* best) {
    int k = blockIdx.x * 256 + threadIdx.x;
    if (k >= NE) return;
    int u = ei[k], v = ei[NE + k];
    float sc = (float)(e_d[k] / ssum[v] + 0.5);
    score[k] = sc;
    u32 m = enc_f(sc);
    u64 kk = ((u64)(m ^ 0xFFFFFFFFu) << 32) | (u32)k;  // low = high score, tie: low idx
    key[k] = kk;
    sel[k] = 0;
    act0[k] = k;
    atomicMin(&best[u], kk);
    atomicMin(&best[v], kk);
}

// ---------------- flattened dominant-edge peeling rounds ----------------
__global__ void mk_sel(const u64* __restrict__ key, const int* __restrict__ ei,
                       const int* __restrict__ act, const int* __restrict__ cntp,
                       int* ncntp, const u64* __restrict__ best,
                       u32* used, int* sel) {
    int cnt = cntp[0];
    int stride = gridDim.x * blockDim.x;
    int gid = blockIdx.x * blockDim.x + threadIdx.x;
    if (gid == 0) ncntp[0] = 0;
    for (int i = gid; i < cnt; i += stride) {
        int e = act[i];
        u64 k = key[e];
        int a = ei[e], b = ei[NE + e];
        if (best[a] == k && best[b] == k) { sel[e] = 1; used[a] = 1u; used[b] = 1u; }
    }
}
__global__ void mk_compact(const int* __restrict__ ei, const int* __restrict__ act,
                           const int* __restrict__ cntp, int* nxt, int* ncntp,
                           u64* best, const u32* __restrict__ used) {
    int cnt = cntp[0];
    int stride = gridDim.x * blockDim.x;
    for (int i = blockIdx.x * blockDim.x + threadIdx.x; i < cnt; i += stride) {
        int e = act[i];
        int a = ei[e], b = ei[NE + e];
        best[a] = ~0ull; best[b] = ~0ull;
        bool live = !(used[a] | used[b]);
        u64 mask = __ballot(live);
        if (mask) {
            int lane = threadIdx.x & 63;
            int leader = __ffsll((unsigned long long)mask) - 1;
            int base = 0;
            if (lane == leader) base = atomicAdd(ncntp, __popcll(mask));
            base = __shfl(base, leader, 64);
            if (live) nxt[base + __popcll(mask & ((1ull << lane) - 1ull))] = e;
        }
    }
}
__global__ void mk_min(const u64* __restrict__ key, const int* __restrict__ ei,
                       const int* __restrict__ act, const int* __restrict__ cntp,
                       u64* best) {
    int cnt = cntp[0];
    int stride = gridDim.x * blockDim.x;
    for (int i = blockIdx.x * blockDim.x + threadIdx.x; i < cnt; i += stride) {
        int e = act[i];
        u64 k = key[e];
        atomicMin(&best[ei[e]], k);
        atomicMin(&best[ei[NE + e]], k);
    }
}
__global__ void __launch_bounds__(1024) match_fin(
        const u64* __restrict__ key, const int* __restrict__ ei,
        int* sel, u64* best, u32* used,
        int* listA, int* listB, const int* __restrict__ cntp) {
    int tid = threadIdx.x;
    int cnt = cntp[0];
    int* cur = listA; int* nxt = listB;
    __shared__ int s_n;
    for (int round = 0; round < 4096 && cnt > 0; ++round) {
        for (int i = tid; i < cnt; i += 1024) {
            int e = cur[i]; u64 k = key[e];
            atomicMin(&best[ei[e]], k);
            atomicMin(&best[ei[NE + e]], k);
        }
        __syncthreads();
        for (int i = tid; i < cnt; i += 1024) {
            int e = cur[i]; u64 k = key[e];
            int a = ei[e], b = ei[NE + e];
            if (best[a] == k && best[b] == k) { sel[e] = 1; used[a] = 1u; used[b] = 1u; }
        }
        if (tid == 0) s_n = 0;
        __syncthreads();
        for (int i = tid; i < cnt; i += 1024) {
            int e = cur[i];
            int a = ei[e], b = ei[NE + e];
            best[a] = ~0ull; best[b] = ~0ull;
            if (!(used[a] | used[b])) {
                int idx = atomicAdd(&s_n, 1);
                nxt[idx] = e;
            }
        }
        __syncthreads();
        cnt = s_n;
        int* t = cur; cur = nxt; nxt = t;
        __syncthreads();
    }
}

// apply_sel + ht init + cin zero (grid = NE/256; KEY dead here)
__global__ void apply_sel(const int* __restrict__ ei, const int* __restrict__ sel,
                          const float* __restrict__ score,
                          int* cluster, int* other, float* nscore,
                          u32* ht, u32* cin) {
    int e = blockIdx.x * 256 + threadIdx.x;
    ht[e << 1] = 0xFFFFFFFFu;
    ht[(e << 1) + 1] = 0xFFFFFFFFu;
    if (e < NN) cin[e] = 0u;
    if (sel[e] != 1) return;
    int u = ei[e], v = ei[NE + e];
    int rep = min(u, v);
    cluster[u] = rep; cluster[v] = rep;
    if (u != v) other[rep] = u + v - rep;
    nscore[rep] = score[e];
}

// ---------------- coarse graph: dedup (cu,cv) pairs via hash set ----------------
__global__ void coarse_build(const int* __restrict__ ei, const int* __restrict__ cluster,
                             u32* ht, int* misc, int* ce_u, int* ce_v, u32* deg,
                             u32* cin) {
    int e = blockIdx.x * 256 + threadIdx.x;
    if (e >= NE) return;
    int cu = cluster[ei[e]], cv = cluster[ei[NE + e]];
    if (cu == cv) return;
    u32 k = (u32)cu * 32768u + (u32)cv;
    u32 h = ((k * 2654435761u) >> 12) & HTM;
    while (true) {
        u32 old = atomicCAS(&ht[h], 0xFFFFFFFFu, k);
        if (old == 0xFFFFFFFFu) {
            int idx = atomicAdd(&misc[0], 1);
            ce_u[idx] = cu; ce_v[idx] = cv;
            atomicAdd(&deg[cu], 1u);
            atomicAdd(&cin[cv], 1u);
            break;
        }
        if (old == k) break;
        h = (h + 1) & HTM;
    }
}
// dis + readout-scratch zero + gcnt (per-wave ballot reduction; batch sorted)
__global__ void dis_kernel(const u32* __restrict__ deg, float* dis,
                           float* racc1, float* racc2,
                           const int* __restrict__ clus, const int* __restrict__ batch,
                           float* gcnt) {
    int n = blockIdx.x * 256 + threadIdx.x;
    if (n >= NN) return;
    u32 d = deg[n];
    dis[n] = d ? (float)(1.0 / sqrt((double)d)) : 0.0f;
    if (n < 4096) racc1[n] = 0.0f;
    if (n < 2048) racc2[n] = 0.0f;
    bool val = (clus[n] == n);
    int bt = batch[n];
    int lane = threadIdx.x & 63;
    #pragma unroll
    for (int g = 0; g < 8; ++g) {
        u64 m = __ballot(val && bt == g);
        if (m && lane == (__ffsll((unsigned long long)m) - 1))
            unsafeAtomicAdd(&gcnt[g], (float)__popcll(m));
    }
}

// ---------------- multi-block CSR/compaction scan (3 kernels) ----------------
// pass 1: per-256-elem block sums of cin and valid
__global__ void __launch_bounds__(256) scan_part(const u32* __restrict__ cin,
                                                 const int* __restrict__ clus,
                                                 int* __restrict__ bsum) {
    int t = threadIdx.x;
    int i = blockIdx.x * 256 + t;
    int vc = (int)cin[i];
    int vv = (clus[i] == i) ? 1 : 0;
    #pragma unroll
    for (int off = 32; off > 0; off >>= 1) {
        vc += __shfl_down(vc, off, 64);
        vv += __shfl_down(vv, off, 64);
    }
    __shared__ int sc[4], sv[4];
    if ((t & 63) == 0) { sc[t >> 6] = vc; sv[t >> 6] = vv; }
    __syncthreads();
    if (t == 0) {
        bsum[blockIdx.x] = sc[0] + sc[1] + sc[2] + sc[3];
        bsum[128 + blockIdx.x] = sv[0] + sv[1] + sv[2] + sv[3];
    }
}
// pass 2: exclusive scan of the 128 block sums (both arrays); misc[4] = total valid
__global__ void __launch_bounds__(128) scan_mid(const int* __restrict__ bsum,
                                                int* __restrict__ boff, int* misc) {
    __shared__ int s[256];
    int t = threadIdx.x;
    int v0 = bsum[t], v1 = bsum[128 + t];
    s[t] = v0; s[128 + t] = v1;
    __syncthreads();
    for (int d = 1; d < 128; d <<= 1) {
        int a = (t >= d) ? s[t - d] : 0;
        int b = (t >= d) ? s[128 + t - d] : 0;
        __syncthreads();
        if (t >= d) { s[t] += a; s[128 + t] += b; }
        __syncthreads();
    }
    boff[t] = s[t] - v0;            // exclusive
    boff[128 + t] = s[128 + t] - v1;
    if (t == 127) misc[4] = s[255];
}
// pass 3: intra-block exclusive scan (packed (cin<<9)|valid; per-block valid sum
// <= 256 < 512 so the 9-bit field never overflows) + block offset + final writes
__global__ void __launch_bounds__(256) scan_fin(const u32* __restrict__ cin,
                                                const int* __restrict__ clus,
                                                const int* __restrict__ boff,
                                                int* off, int* cur, int* cidx, int* perm) {
    __shared__ int s[256];
    int t = threadIdx.x;
    int i = blockIdx.x * 256 + t;
    int vc = (int)cin[i];
    int vv = (clus[i] == i) ? 1 : 0;
    int p = (vc << 9) | vv;
    s[t] = p;
    __syncthreads();
    for (int d = 1; d < 256; d <<= 1) {
        int a = (t >= d) ? s[t - d] : 0;
        __syncthreads();
        if (t >= d) s[t] += a;
        __syncthreads();
    }
    int ex = s[t] - p;   // exclusive packed prefix
    int o = boff[blockIdx.x] + (ex >> 9);
    off[i] = o; cur[i] = o;
    int c = boff[128 + blockIdx.x] + (ex & 511);
    cidx[i] = c;
    if (vv) perm[c] = i;
}

// csr_a stores COMPACT source row indices (cidx available: scan runs first)
__global__ void csr_scatter(const int* __restrict__ ce_u, const int* __restrict__ ce_v,
                            const float* __restrict__ dis, const int* __restrict__ misc,
                            int* cur, int* csr_a, float* csr_c,
                            const int* __restrict__ cidx) {
    int e = blockIdx.x * 256 + threadIdx.x;
    if (e >= misc[0]) return;
    int a = ce_u[e], b = ce_v[e];
    int pos = atomicAdd(&cur[b], 1);
    csr_a[pos] = cidx[a];
    csr_c[pos] = -dis[a] * dis[b];
}

// ---- packed fragment index: row r, col k -> ushort offset ----
__device__ __forceinline__ size_t pk_idx(int r, int k, int KT) {
    return ((((size_t)(r >> 4) * KT + (k >> 5)) << 6) + (((k >> 3) & 3) << 4) + (r & 15)) << 3;
}

// ---------------- fused: packed Ax gather (COMPACT rows, LDS-staged coalesced) ----------------
__global__ void __launch_bounds__(256) conv_all(
        const float* __restrict__ x, const int* __restrict__ perm,
        const int* __restrict__ misc,
        const int* __restrict__ other, const float* __restrict__ nsc,
        unsigned short* __restrict__ Abf, float* __restrict__ pxl,
        const float* __restrict__ B10, const float* __restrict__ B11,
        unsigned short* __restrict__ Bp1,
        const float* __restrict__ B20, const float* __restrict__ B21,
        unsigned short* __restrict__ Bp2) {
    int bid = blockIdx.x;
    int t = threadIdx.x;
    if (bid < 2048) {   // A-tile gather via coalesced row staging in LDS
        __shared__ unsigned short S[16][1032];   // +8 ushort pad: 2-way max bank alias
        __shared__ int Srow[16], So[16];
        __shared__ float Ss[16];
        int cnt = misc[4];
        int tile = bid;
        if ((tile << 4) >= ((cnt + 127) & ~127)) return;  // beyond padded M': unread
        if (t < 16) {
            int ci = (tile << 4) + t;
            bool val = ci < cnt;
            int row = val ? perm[ci] : -1;
            Srow[t] = row;
            So[t] = val ? other[row] : -1;
            Ss[t] = val ? nsc[row] : 0.0f;
        }
        __syncthreads();
        if (t < 16) {   // pxl (col 1024), 16 scattered scalar loads — tiny
            int row = Srow[t];
            float v = 0.0f;
            if (row >= 0) {
                int o = So[t];
                v = x[(size_t)row * FIN + 1024];
                if (o >= 0) v += x[(size_t)o * FIN + 1024];
                v *= Ss[t];
            }
            pxl[(tile << 4) + t] = v;
        }
        // stage 16 rows: lane t reads cols t, t+256, t+512, t+768 — fully coalesced,
        // all loads independent across k and r (deep MLP)
        for (int r = 0; r < 16; ++r) {
            int row = Srow[r];          // wave-uniform
            int o = So[r];
            float s = Ss[r];
            if (row >= 0) {
                const float* xr = x + (size_t)row * FIN;
                const float* xo = x + (size_t)(o >= 0 ? o : row) * FIN;
                #pragma unroll
                for (int k = 0; k < 4; ++k) {
                    int c = (k << 8) + t;
                    float v = xr[c];
                    if (o >= 0) v += xo[c];
                    S[r][c] = f2bf(v * s);
                }
            } else {
                #pragma unroll
                for (int k = 0; k < 4; ++k) S[r][(k << 8) + t] = 0;
            }
        }
        __syncthreads();
        // pack: 16B LDS reads -> 16B global stores (identical layout/content as before)
        int wave = t >> 6, lane = t & 63;
        int l16 = lane & 15, quad = lane >> 4;
        #pragma unroll
        for (int kt0 = 0; kt0 < 8; ++kt0) {
            int kt = (kt0 << 2) + wave;
            int c0 = (kt << 5) + (quad << 3);
            us8 v = *(const us8*)&S[l16][c0];
            *(us8*)&Abf[((((size_t)tile << 5) + kt) << 9) + ((size_t)lane << 3)] = v;
        }
    } else if (bid < 2560) {   // L1 weight transpose, KT=32
        int j = bid - 2048;
        int n = ((j & 3) << 8) + t;
        int k0 = (j >> 2) << 3;
        unsigned short h[8];
        #pragma unroll
        for (int jj = 0; jj < 8; ++jj) {
            int k = k0 + jj;
            float v = (n < 512) ? B10[(size_t)k * 512 + n] : B11[(size_t)k * 512 + (n - 512)];
            h[jj] = f2bf(v);
        }
        *(us8*)&Bp1[pk_idx(n, k0, 32)] = *(const us8*)h;
    } else {                   // L2 weight transpose, KT=16
        int j = bid - 2560;
        int n = ((j & 3) << 8) + t;
        int k0 = (j >> 2) << 3;
        unsigned short h[8];
        #pragma unroll
        for (int jj = 0; jj < 8; ++jj) {
            int k = k0 + jj;
            float v = (n < 512) ? B20[(size_t)k * 512 + n] : B21[(size_t)k * 512 + (n - 512)];
            h[jj] = f2bf(v);
        }
        *(us8*)&Bp2[pk_idx(n, k0, 16)] = *(const us8*)h;
    }
}

// ---------------- packed-fragment bf16 MFMA GEMM with LDS DMA double-buffer ----------------
// Transposed-output form: acc[ni][mi] = mfma(bf, af) computes D^T fragments, so each
// lane holds 4 CONSECUTIVE N-columns at a fixed M-row -> direct float4/us4 stores.
// (256,4): r9 showed (256,5) thrashes L2/L3 (FETCH 28->150 MB) and constrains VGPR
// (60->48), halving MfmaUtil — occupancy-forcing refuted, keep 4 blocks/CU.
template <bool R1>
__global__ void __launch_bounds__(256, 4) gemm_pk(
        const unsigned short* __restrict__ Ap, const unsigned short* __restrict__ Bp,
        float* __restrict__ P, unsigned short* __restrict__ Pb, int KT,
        const float* __restrict__ pxl, const float* __restrict__ w0,
        const float* __restrict__ w1, const int* __restrict__ msc) {
    __shared__ unsigned short L[2][8192];
    int tid = threadIdx.x;
    int bid = blockIdx.x;
    int bn = (bid & 7) << 7;
    int bm = (bid >> 3) << 7;                    // dead blocks = contiguous grid tail
    if (bm >= ((msc[4] + 127) & ~127)) return;   // zero-row block: output never read
    int wave = tid >> 6, lane = tid & 63, quad = lane >> 4, l16 = lane & 15;
    int moff = (wave >> 1) << 6, noff = (wave & 1) << 6;
    f32x4 acc[4][4];   // [ni][mi] — transposed-output fragments
    #pragma unroll
    for (int i = 0; i < 4; ++i)
        #pragma unroll
        for (int j = 0; j < 4; ++j) acc[i][j] = (f32x4){0.f, 0.f, 0.f, 0.f};

    const unsigned short* src[4];
    unsigned short* dst[4];
    #pragma unroll
    for (int q = 0; q < 4; ++q) {
        int f = (wave << 2) + q;
        int tg = (f < 8) ? ((bm >> 4) + f) : ((bn >> 4) + (f - 8));
        src[q] = ((f < 8) ? Ap : Bp) + (((size_t)tg * KT) << 9) + ((size_t)lane << 3);
        dst[q] = &L[0][(size_t)f << 9];
    }
    const unsigned short* ra = &L[0][(size_t)(wave >> 1) << 11];
    const unsigned short* rb = &L[0][4096 + ((size_t)(wave & 1) << 11)];

    #pragma unroll
    for (int q = 0; q < 4; ++q) dma16(dst[q], src[q]);
    __syncthreads();

    int cur = 0;
    for (int kt = 0; kt < KT; ++kt) {
        if (kt + 1 < KT) {
            int nb = (cur ^ 1) * 8192;
            size_t go = ((size_t)(kt + 1)) << 9;
            #pragma unroll
            for (int q = 0; q < 4; ++q) dma16(dst[q] + nb, src[q] + go);
        }
        const unsigned short* la = ra + cur * 8192;
        const unsigned short* lb = rb + cur * 8192;
        bf16x8 af[4], bf[4];
        #pragma unroll
        for (int i = 0; i < 4; ++i) {
            af[i] = ld_frag(la + ((size_t)i << 9) + (lane << 3));
            bf[i] = ld_frag(lb + ((size_t)i << 9) + (lane << 3));
        }
        #pragma unroll
        for (int ni = 0; ni < 4; ++ni)
            #pragma unroll
            for (int mi = 0; mi < 4; ++mi)
                acc[ni][mi] = __builtin_amdgcn_mfma_f32_16x16x32_bf16(bf[ni], af[mi], acc[ni][mi], 0, 0, 0);
        __syncthreads();
        cur ^= 1;
    }
    // ---- epilogue: D^T fragment: n = bn+noff+ni*16+quad*4+r2, m = bm+moff+mi*16+l16.
    // 4 consecutive n per lane -> float4 (P) / us4 (Pb) stores; rank-1 weight is a
    // contiguous float4 load. Blocks are pure-P (bn<512) or pure-Pb (bn multiple of 128).
    #pragma unroll
    for (int mi = 0; mi < 4; ++mi) {
        int m = bm + moff + (mi << 4) + l16;
        float pm = 0.0f;
        if (R1) pm = pxl[m];
        #pragma unroll
        for (int ni = 0; ni < 4; ++ni) {
            int n0 = bn + noff + (ni << 4) + (quad << 2);
            float v0 = acc[ni][mi][0], v1 = acc[ni][mi][1];
            float v2 = acc[ni][mi][2], v3 = acc[ni][mi][3];
            if (bn < 512) {
                if (R1) {
                    float4 wv = *(const float4*)&w0[524288 + n0];
                    v0 += pm * wv.x; v1 += pm * wv.y; v2 += pm * wv.z; v3 += pm * wv.w;
                }
                *(float4*)&P[(size_t)m * 512 + n0] = make_float4(v0, v1, v2, v3);
            } else {
                if (R1) {
                    float4 wv = *(const float4*)&w1[524288 + n0 - 512];
                    v0 += pm * wv.x; v1 += pm * wv.y; v2 += pm * wv.z; v3 += pm * wv.w;
                }
                unsigned short h[4] = {f2bf(v0), f2bf(v1), f2bf(v2), f2bf(v3)};
                *(us4*)&Pb[(size_t)m * 512 + (n0 - 512)] = *(const us4*)h;
            }
        }
    }
}

// ---------------- fused gather + BN + ReLU: one wave per COMPACT destination row ----------------
template <bool BF16OUT>
__global__ void __launch_bounds__(256) cheb_fuse(
        const float* __restrict__ P, const unsigned short* __restrict__ Pb,
        const int* __restrict__ off,
        const int* __restrict__ csr_a, const float* __restrict__ csr_c,
        const int* __restrict__ misc, const float* __restrict__ bias,
        const float* __restrict__ bn, float* __restrict__ Hf,
        unsigned short* __restrict__ Hb, const int* __restrict__ perm) {
    int b = (blockIdx.x * 256 + threadIdx.x) >> 6;
    int lane = threadIdx.x & 63;
    if (b >= misc[4]) return;
    int r = perm[b];
    int s = off[r];
    int e = (r < NN - 1) ? off[r + 1] : misc[0];
    int c0 = lane << 3;
    float a0[4], a1[4];
    {
        float4 t0 = *(const float4*)&P[(size_t)b * 512 + c0];
        float4 t1 = *(const float4*)&P[(size_t)b * 512 + c0 + 4];
        a0[0] = t0.x; a0[1] = t0.y; a0[2] = t0.z; a0[3] = t0.w;
        a1[0] = t1.x; a1[1] = t1.y; a1[2] = t1.z; a1[3] = t1.w;
    }
    for (int j = s; j < e; ++j) {
        int a = csr_a[j];          // already a compact row index
        float cf = csr_c[j];
        us8 raw = *(const us8*)&Pb[(size_t)a * 512 + c0];
        a0[0] = fmaf(cf, bf2f(raw[0]), a0[0]); a0[1] = fmaf(cf, bf2f(raw[1]), a0[1]);
        a0[2] = fmaf(cf, bf2f(raw[2]), a0[2]); a0[3] = fmaf(cf, bf2f(raw[3]), a0[3]);
        a1[0] = fmaf(cf, bf2f(raw[4]), a1[0]); a1[1] = fmaf(cf, bf2f(raw[5]), a1[1]);
        a1[2] = fmaf(cf, bf2f(raw[6]), a1[2]); a1[3] = fmaf(cf, bf2f(raw[7]), a1[3]);
    }
    float o[8];
    #pragma unroll
    for (int i = 0; i < 8; ++i) {
        int j = c0 + i;
        float acc = (i < 4) ? a0[i] : a1[i - 4];
        float ga = bn[j], be = bn[512 + j], mn = bn[1024 + j], vr = bn[1536 + j];
        float sc = (float)(1.0 / sqrt((double)vr + 1e-5));
        float v = (acc + bias[j] - mn) * sc * ga + be;
        o[i] = v > 0.0f ? v : 0.0f;
    }
    if (BF16OUT) {
        unsigned short h[8];
        #pragma unroll
        for (int i = 0; i < 8; ++i) h[i] = f2bf(o[i]);
        *(us8*)&Hb[pk_idx(b, c0, 16)] = *(const us8*)h;   // packed for layer-2 GEMM
    } else {
        *(float4*)&Hf[(size_t)b * 512 + c0] = make_float4(o[0], o[1], o[2], o[3]);
        *(float4*)&Hf[(size_t)b * 512 + c0 + 4] = make_float4(o[4], o[5], o[6], o[7]);
    }
}

// ---------------- global max+mean pool over valid nodes per graph ----------------
// H rows are compact; gather via cidx[n] (monotone over n -> stays coalesced).
// 2048 blocks x 16 nodes: 8 blocks/CU (vs 2 at 64-node chunks) — latency-bound fix.
__global__ void __launch_bounds__(256) pool_kernel(
        const float* __restrict__ H, const int* __restrict__ cluster,
        const int* __restrict__ batch, u32* gmaxb, float* gsum,
        const int* __restrict__ cidx) {
    int t = threadIdx.x;
    int n0 = blockIdx.x * 16;
    float m0 = 0.0f, m1 = 0.0f, s0 = 0.0f, s1 = 0.0f;
    int cur = batch[n0];
    for (int i = 0; i < 16; ++i) {
        int n = n0 + i;
        int bt = batch[n];
        if (bt != cur) {
            atomicMax(&gmaxb[cur * 512 + t], __float_as_uint(m0));
            atomicMax(&gmaxb[cur * 512 + t + 256], __float_as_uint(m1));
            unsafeAtomicAdd(&gsum[cur * 512 + t], s0);
            unsafeAtomicAdd(&gsum[cur * 512 + t + 256], s1);
            m0 = m1 = s0 = s1 = 0.0f; cur = bt;
        }
        if (cluster[n] == n) {
            size_t ci = (size_t)cidx[n];
            float h0 = H[ci * 512 + t];
            float h1 = H[ci * 512 + t + 256];
            m0 = fmaxf(m0, h0); m1 = fmaxf(m1, h1);
            s0 += h0; s1 += h1;
        }
    }
    atomicMax(&gmaxb[cur * 512 + t], __float_as_uint(m0));
    atomicMax(&gmaxb[cur * 512 + t + 256], __float_as_uint(m1));
    unsafeAtomicAdd(&gsum[cur * 512 + t], s0);
    unsafeAtomicAdd(&gsum[cur * 512 + t + 256], s1);
}

// ---------------- parallel readout MLP (3 kernels) ----------------
__global__ void __launch_bounds__(512) ro1(
        const u32* __restrict__ gmaxb, const float* __restrict__ gsum,
        const float* __restrict__ gcnt, const float* __restrict__ l1w,
        float* __restrict__ racc1) {
    int o = threadIdx.x;
    int k0 = blockIdx.x << 4;
    float acc[8] = {0, 0, 0, 0, 0, 0, 0, 0};
    float inv[8];
    #pragma unroll
    for (int b = 0; b < 8; ++b) inv[b] = 1.0f / fmaxf(gcnt[b], 1.0f);
    for (int kk = 0; kk < 16; ++kk) {
        int k = k0 + kk;
        float w = l1w[(size_t)k * 512 + o];
        #pragma unroll
        for (int b = 0; b < 8; ++b) {
            float g = (k < 512) ? __uint_as_float(gmaxb[b * 512 + k])
                                : gsum[b * 512 + (k - 512)] * inv[b];
            acc[b] = fmaf(g, w, acc[b]);
        }
    }
    #pragma unroll
    for (int b = 0; b < 8; ++b) unsafeAtomicAdd(&racc1[b * 512 + o], acc[b]);
}
// ro3: layer-2 partials with ro2's BN inlined (recomputed per k-slice)
__global__ void __launch_bounds__(256) ro3(
        const float* __restrict__ racc1, const float* __restrict__ l1b,
        const float* __restrict__ bn3, const float* __restrict__ l2w,
        float* __restrict__ racc2) {
    int o = threadIdx.x;
    int k0 = blockIdx.x << 4;
    float acc[8] = {0, 0, 0, 0, 0, 0, 0, 0};
    for (int kk = 0; kk < 16; ++kk) {
        int k = k0 + kk;
        float ga = bn3[k], be = bn3[512 + k], mn = bn3[1024 + k], vr = bn3[1536 + k];
        float sc = (float)(1.0 / sqrt((double)vr + 1e-5));
        float bi = l1b[k];
        float w = l2w[(size_t)k * 256 + o];
        #pragma unroll
        for (int b = 0; b < 8; ++b) {
            float g1 = (racc1[b * 512 + k] + bi - mn) * sc * ga + be;
            g1 = g1 > 0.0f ? g1 : 0.0f;
            acc[b] = fmaf(g1, w, acc[b]);
        }
    }
    #pragma unroll
    for (int b = 0; b < 8; ++b) unsafeAtomicAdd(&racc2[b * 256 + o], acc[b]);
}
__global__ void __launch_bounds__(256) ro4(
        const float* __restrict__ racc2, const float* __restrict__ l2b,
        const float* __restrict__ bn4, const float* __restrict__ l3w,
        const float* __restrict__ l3b, float* __restrict__ out) {
    __shared__ float G2[8 * 256];
    int o = threadIdx.x;
    {
        float ga = bn4[o], be = bn4[256 + o], mn = bn4[512 + o], vr = bn4[768 + o];
        float sc = (float)(1.0 / sqrt((double)vr + 1e-5));
        float bi = l2b[o];
        #pragma unroll
        for (int b = 0; b < 8; ++b) {
            float v = (racc2[b * 256 + o] + bi - mn) * sc * ga + be;
            v = v > 0.0f ? v : 0.0f;
            G2[b * 256 + o] = v;
            out[32 + b * 256 + o] = v;
        }
    }
    __syncthreads();
    if (o < 8) {
        int b = o;
        float r[4];
        #pragma unroll
        for (int c = 0; c < 4; ++c) {
            float acc = l3b[c];
            for (int k = 0; k < 256; ++k) acc += G2[b * 256 + k] * l3w[k * 4 + c];
            r[c] = acc > 0.0f ? acc : 0.0f;
        }
        float mx = fmaxf(fmaxf(r[0], r[1]), fmaxf(r[2], r[3]));
        float s = 0.0f;
        #pragma unroll
        for (int c = 0; c < 4; ++c) s += expf(r[c] - mx);
        float lse = mx + logf(s);
        #pragma unroll
        for (int c = 0; c < 4; ++c) out[b * 4 + c] = r[c] - lse;
    }
}

extern "C" void kernel_launch(void* const* d_in, const int* in_sizes, int n_in,
                              void* d_out, int out_size, void* d_ws, size_t ws_size,
                              hipStream_t stream) {
    const float* x      = (const float*)d_in[0];
    const int*   ei     = (const int*)d_in[1];
    const int*   batch  = (const int*)d_in[2];
    const float* pool_w = (const float*)d_in[3];
    const float* pool_b = (const float*)d_in[4];
    const float* c1_w0  = (const float*)d_in[5];
    const float* c1_w1  = (const float*)d_in[6];
    const float* c1_b   = (const float*)d_in[7];
    const float* c2_w0  = (const float*)d_in[8];
    const float* c2_w1  = (const float*)d_in[9];
    const float* c2_b   = (const float*)d_in[10];
    const float* bn1    = (const float*)d_in[11];
    const float* bn2    = (const float*)d_in[12];
    const float* bn3    = (const float*)d_in[13];
    const float* bn4    = (const float*)d_in[14];
    const float* l1w    = (const float*)d_in[15];
    const float* l1b    = (const float*)d_in[16];
    const float* l2w    = (const float*)d_in[17];
    const float* l2b    = (const float*)d_in[18];
    const float* l3w    = (const float*)d_in[19];
    const float* l3b    = (const float*)d_in[20];
    float* out = (float*)d_out;
    char* ws = (char*)d_ws;

    double* a_d   = (double*)(ws + WS_A_D);
    double* b_d   = (double*)(ws + WS_B_D);
    u32*    emax  = (u32*)(ws + WS_EMAX);
    double* ssum  = (double*)(ws + WS_SSUM);
    double* exd   = (double*)(ws + WS_EXD);
    u32*    cin   = (u32*)(ws + WS_CIN);
    int*    cidxp = (int*)(ws + WS_CIDX);
    int*    permp = (int*)(ws + WS_PERM);
    int*    bsum  = (int*)(ws + WS_BSUM);
    int*    boffp = (int*)(ws + WS_BOFF);
    u64*    key   = (u64*)(ws + WS_KEY);
    u64*    best  = (u64*)(ws + WS_BEST);
    u32*    used  = (u32*)(ws + WS_USED);
    int*    curp  = (int*)(ws + WS_CUR);
    int*    act0  = (int*)(ws + WS_ACT0);
    int*    act1  = (int*)(ws + WS_ACT1);
    unsigned short* bthi = (unsigned short*)(ws + WS_BTHI);
    unsigned short* bt2  = (unsigned short*)(ws + WS_BT2);
    float*  pxl   = (float*)(ws + WS_PXL);
    u32*    ht    = (u32*)(ws + WS_HT);
    float*  racc1 = (float*)(ws + WS_RACC1);
    float*  racc2 = (float*)(ws + WS_RACC2);
    float*  score = (float*)(ws + WS_SCORE);
    int*    csr_a = (int*)(ws + WS_CSRA);
    int*    sel   = (int*)(ws + WS_SEL);
    float*  csr_c = (float*)(ws + WS_CSRC);
    int*    clus  = (int*)(ws + WS_CLUST);
    int*    other = (int*)(ws + WS_OTHER);
    float*  nsc   = (float*)(ws + WS_NSC);
    int*    ce_u  = (int*)(ws + WS_CEU);
    int*    ce_v  = (int*)(ws + WS_CEV);
    u32*    deg   = (u32*)(ws + WS_DEG);
    int*    off   = (int*)(ws + WS_OFF);
    float*  dis   = (float*)(ws + WS_DIS);
    int*    misc  = (int*)(ws + WS_MISC);
    u32*    gmaxb = (u32*)(ws + WS_GMAX);
    float*  gsum  = (float*)(ws + WS_GSUM);
    float*  gcnt  = (float*)(ws + WS_GCNT);
    float*  P     = (float*)(ws + WS_P);
    unsigned short* Pb = (unsigned short*)(ws + WS_PB);
    unsigned short* ax = (unsigned short*)(ws + WS_H);   // packed Ax bf16 (gemm1 A)
    unsigned short* hb = (unsigned short*)(ws + WS_H);   // packed Hb bf16 (gemm2 A)
    float*  H     = (float*)(ws + WS_H);                 // final H fp32

    // ---- phase A: scores, matching, coarse graph ----
    node_dots<<<NN / 4, 256, 0, stream>>>(x, pool_w, a_d, b_d,
                                          emax, ssum, deg, misc, gmaxb, gsum, gcnt,
                                          best, used, clus, other, nsc);
    edge_p1<<<NE / 256, 256, 0, stream>>>(ei, a_d, b_d, pool_b, exd, emax);
    edge_p2<<<NE / 256, 256, 0, stream>>>(ei, exd, emax, ssum);
    edge_p3<<<NE / 256, 256, 0, stream>>>(ei, exd, ssum, score, key, sel, act0, best);

    {
        // 4 flattened rounds (was 8): rounds 5-8 ran on tiny lists where launch
        // overhead dominates; match_fin absorbs them in-block. Parity preserved:
        // after r=3 (odd), count in misc[1], active list in act0 — same as before.
        static const int gr[5] = {512, 512, 256, 128, 64};
        int* acts[2] = {act0, act1};
        for (int r = 0; r < 4; ++r) {
            int c = r & 1, n = 1 - c;
            mk_sel<<<gr[r], 256, 0, stream>>>(key, ei, acts[c], &misc[1 + c],
                                              &misc[1 + n], best, used, sel);
            mk_compact<<<gr[r], 256, 0, stream>>>(ei, acts[c], &misc[1 + c],
                                                  acts[n], &misc[1 + n], best, used);
            mk_min<<<gr[r + 1], 256, 0, stream>>>(key, ei, acts[n], &misc[1 + n], best);
        }
        match_fin<<<1, 1024, 0, stream>>>(key, ei, sel, best, used,
                                          act0, act1, &misc[1]);
    }

    apply_sel<<<NE / 256, 256, 0, stream>>>(ei, sel, score, clus, other, nsc, ht, cin);
    coarse_build<<<NE / 256, 256, 0, stream>>>(ei, clus, ht, misc, ce_u, ce_v, deg, cin);
    dis_kernel<<<NN / 256, 256, 0, stream>>>(deg, dis, racc1, racc2, clus, batch, gcnt);
    scan_part<<<128, 256, 0, stream>>>(cin, clus, bsum);
    scan_mid<<<1, 128, 0, stream>>>(bsum, boffp, misc);
    scan_fin<<<128, 256, 0, stream>>>(cin, clus, boffp, off, curp, cidxp, permp);
    csr_scatter<<<NE / 256, 256, 0, stream>>>(ce_u, ce_v, dis, misc, curp, csr_a, csr_c,
                                              cidxp);

    // ---- phase B: ChebConv layers on COMPACT rows (misc[4] ~ 0.55*NN survive) ----
    conv_all<<<2816, 256, 0, stream>>>(x, permp, misc, other, nsc, ax, pxl,
                                       c1_w0, c1_w1, bthi, c2_w0, c2_w1, bt2);
    gemm_pk<true><<<2048, 256, 0, stream>>>(ax, bthi, P, Pb, 32, pxl, c1_w0, c1_w1, misc);
    cheb_fuse<true><<<NN / 4, 256, 0, stream>>>(P, Pb, off, csr_a, csr_c, misc, c1_b, bn1,
                                                nullptr, hb, permp);

    gemm_pk<false><<<2048, 256, 0, stream>>>(hb, bt2, P, Pb, 16, nullptr, nullptr, nullptr,
                                             misc);
    cheb_fuse<false><<<NN / 4, 256, 0, stream>>>(P, Pb, off, csr_a, csr_c, misc, c2_b, bn2,
                                                 H, nullptr, permp);

    pool_kernel<<<NN / 16, 256, 0, stream>>>(H, clus, batch, gmaxb, gsum, cidxp);

    // ---- parallel readout ----
    ro1<<<64, 512, 0, stream>>>(gmaxb, gsum, gcnt, l1w, racc1);
    ro3<<<32, 256, 0, stream>>>(racc1, l1b, bn3, l2w, racc2);
    ro4<<<1, 256, 0, stream>>>(racc2, l2b, bn4, l3w, l3b, out);
}

// Round 11
// 711.456 us; speedup vs baseline: 1.1184x; 1.0113x over previous
//
#include <hip/hip_runtime.h>
#include <hip/hip_bf16.h>
#include <cstdint>
#include <cmath>

typedef unsigned int u32;
typedef unsigned long long u64;
typedef float f32x4 __attribute__((ext_vector_type(4)));
typedef __bf16 bf16x8 __attribute__((ext_vector_type(8)));
typedef unsigned short us8 __attribute__((ext_vector_type(8)));
typedef unsigned short us4 __attribute__((ext_vector_type(4)));

#define NN 32768
#define NE 131072
#define FIN 1025
#define HTS 262144
#define HTM (HTS - 1)

// ---------------- workspace layout (byte offsets) ----------------
#define WS_A_D    0ul          // double[NN]
#define WS_B_D    262144ul     // double[NN]
#define WS_EMAX   524288ul     // u32[NN]
#define WS_SSUM   655360ul     // double[NN]
#define WS_EXD    917504ul     // double[NE]
#define WS_CIN    917504ul     // u32[NN]  overlays EXD head (zeroed in apply_sel)
#define WS_KEY    1966080ul    // u64[NE]
#define WS_BEST   3014656ul    // u64[NN]
#define WS_USED   3276800ul    // u32[NN]
#define WS_CUR    3276800ul    // int[NN]  overlays USED (dead after match_fin)
#define WS_ACT0   3407872ul    // int[NE]
#define WS_ACT1   3932160ul    // int[NE]   (zone ends 4456448)
#define WS_BTHI   0ul          // ushort[1024*1024] packed L1 weights (phase B, 0..2097152)
#define WS_BT2    3407872ul    // ushort[1024*512] packed L2 weights (overlays ACT0/1)
#define WS_HT     1966080ul    // u32[HTS] overlays KEY (init in apply_sel, dead after coarse_build)
// readout scratch (phase B, overlays dead KEY tail):
#define WS_RACC1  2097152ul    // float[8*512]   (..2113536)
#define WS_RACC2  2113536ul    // float[8*256]   (..2121728)
// compaction maps: overlay dead HT/KEY tail, AFTER racc2, clear of BTHI (2097152+)
#define WS_CIDX   2129920ul    // int[NN]  node->compact  (..2260992)
#define WS_PERM   2260992ul    // int[NN]  compact->node  (..2392064)
#define WS_BSUM   2392064ul    // int[256] scan block sums (..2393088)
#define WS_BOFF   2393088ul    // int[256] scan block offsets (..2394112, < 3014656 OK)
// persistent:
#define WS_SCORE  4456448ul    // float[NE]
#define WS_CSRA   4456448ul    // int[NE]  overlays SCORE (dead after apply_sel)
#define WS_SEL    4980736ul    // int[NE]
#define WS_CSRC   4980736ul    // float[NE] overlays SEL (dead after apply_sel)
#define WS_CLUST  5505024ul    // int[NN]
#define WS_OTHER  5636096ul    // int[NN]
#define WS_NSC    5767168ul    // float[NN]
#define WS_CEU    5898240ul    // int[NE]
#define WS_CEV    6422528ul    // int[NE]
#define WS_DEG    6946816ul    // u32[NN]
#define WS_OFF    6946816ul    // int[NN]  overlays DEG
#define WS_DIS    7077888ul    // float[NN]
#define WS_PXL    7077888ul    // float[NN] overlays DIS (dis dead after csr_scatter)
#define WS_MISC   7208960ul    // int[64]
#define WS_GMAX   7209216ul    // u32[8*512]
#define WS_GSUM   7225600ul    // float[8*512]
#define WS_GCNT   7241984ul    // float[64]
#define WS_P      7242240ul    // float[NN*512] P0 fp32 (compact rows)
#define WS_PB     74351104ul   // ushort[NN*512] P1 bf16 (=WS_P+67108864, compact rows)
#define WS_H      141459968ul  // Ax/Hb bf16 packed -> H f32[NN*512] (compact rows)

__device__ __forceinline__ u32 enc_f(float f) {
    u32 b = __float_as_uint(f);
    return (b & 0x80000000u) ? ~b : (b | 0x80000000u);
}
__device__ __forceinline__ float dec_f(u32 m) {
    return (m & 0x80000000u) ? __uint_as_float(m ^ 0x80000000u) : __uint_as_float(~m);
}
__device__ __forceinline__ double wave_sum(double v) {
    #pragma unroll
    for (int off = 32; off > 0; off >>= 1) v += __shfl_down(v, off, 64);
    return v;
}
__device__ __forceinline__ unsigned short f2bf(float v) {   // RNE f32->bf16
    u32 b = __float_as_uint(v);
    u32 r = b + 0x7FFFu + ((b >> 16) & 1u);
    return (unsigned short)(r >> 16);
}
__device__ __forceinline__ float bf2f(unsigned short h) {
    return __uint_as_float(((u32)h) << 16);
}
__device__ __forceinline__ bf16x8 ld_frag(const unsigned short* p) {
    union { us8 u; bf16x8 b; } t;
    t.u = *(const us8*)p;
    return t.b;
}
// async global->LDS, 16B/lane; lds base must be wave-uniform
__device__ __forceinline__ void dma16(unsigned short* lds, const unsigned short* g) {
    __builtin_amdgcn_global_load_lds((const __attribute__((address_space(1))) u32*)g,
                                     (__attribute__((address_space(3))) u32*)lds, 16, 0, 0);
}

// ---------------- per-node dots + all phase-A init fused ----------------
__global__ void node_dots(const float* __restrict__ x, const float* __restrict__ pw,
                          double* a_d, double* b_d,
                          u32* emax, double* ssum, u32* deg, int* misc,
                          u32* gmaxb, float* gsum, float* gcnt,
                          u64* best, u32* used, int* clus, int* other, float* nsc) {
    int gid = blockIdx.x * blockDim.x + threadIdx.x;
    if (gid < NN) {
        emax[gid] = 0u; ssum[gid] = 0.0; deg[gid] = 0u;
        best[gid] = ~0ull; used[gid] = 0u;
        clus[gid] = gid; other[gid] = -1; nsc[gid] = 1.0f;
    }
    if (gid < 4096) { gmaxb[gid] = 0u; gsum[gid] = 0.0f; }
    if (gid < 64) { misc[gid] = (gid == 1) ? NE : 0; gcnt[gid] = 0.0f; }

    int wave = gid >> 6;
    int lane = threadIdx.x & 63;
    if (wave >= NN) return;
    const float* xr = x + (size_t)wave * FIN;
    double s0 = 0.0, s1 = 0.0;
    for (int f = lane; f < FIN; f += 64) {
        double xv = (double)xr[f];
        s0 += xv * (double)pw[f];
        s1 += xv * (double)pw[FIN + f];
    }
    s0 = wave_sum(s0); s1 = wave_sum(s1);
    if (lane == 0) { a_d[wave] = s0; b_d[wave] = s1; }
}

// ---------------- edge score pipeline ----------------
__global__ void edge_p1(const int* __restrict__ ei, const double* __restrict__ a_d,
                        const double* __restrict__ b_d, const float* __restrict__ pb,
                        double* e_d, u32* emax) {
    int k = blockIdx.x * 256 + threadIdx.x;
    if (k >= NE) return;
    int u = ei[k], v = ei[NE + k];
    double e = a_d[u] + b_d[v] + (double)pb[0];
    e_d[k] = e;
    atomicMax(&emax[v], enc_f((float)e));
}
__global__ void edge_p2(const int* __restrict__ ei, double* e_d,
                        const u32* __restrict__ emax, double* ssum) {
    int k = blockIdx.x * 256 + threadIdx.x;
    if (k >= NE) return;
    int v = ei[NE + k];
    float mf = dec_f(emax[v]);
    double ex = exp(e_d[k] - (double)mf);
    e_d[k] = ex;
    unsafeAtomicAdd(&ssum[v], ex);
}
__global__ void edge_p3(const int* __restrict__ ei, const double* __restrict__ e_d,
                        const double* __restrict__ ssum, float* score, u64* key,
                        int* sel, int* act0, u64* best) {
    int k = blockIdx.x * 256 + threadIdx.x;
    if (k >= NE) return;
    int u = ei[k], v = ei[NE + k];
    float sc = (float)(e_d[k] / ssum[v] + 0.5);
    score[k] = sc;
    u32 m = enc_f(sc);
    u64 kk = ((u64)(m ^ 0xFFFFFFFFu) << 32) | (u32)k;  // low = high score, tie: low idx
    key[k] = kk;
    sel[k] = 0;
    act0[k] = k;
    atomicMin(&best[u], kk);
    atomicMin(&best[v], kk);
}

// ---------------- flattened dominant-edge peeling rounds ----------------
__global__ void mk_sel(const u64* __restrict__ key, const int* __restrict__ ei,
                       const int* __restrict__ act, const int* __restrict__ cntp,
                       int* ncntp, const u64* __restrict__ best,
                       u32* used, int* sel) {
    int cnt = cntp[0];
    int stride = gridDim.x * blockDim.x;
    int gid = blockIdx.x * blockDim.x + threadIdx.x;
    if (gid == 0) ncntp[0] = 0;
    for (int i = gid; i < cnt; i += stride) {
        int e = act[i];
        u64 k = key[e];
        int a = ei[e], b = ei[NE + e];
        if (best[a] == k && best[b] == k) { sel[e] = 1; used[a] = 1u; used[b] = 1u; }
    }
}
__global__ void mk_compact(const int* __restrict__ ei, const int* __restrict__ act,
                           const int* __restrict__ cntp, int* nxt, int* ncntp,
                           u64* best, const u32* __restrict__ used) {
    int cnt = cntp[0];
    int stride = gridDim.x * blockDim.x;
    for (int i = blockIdx.x * blockDim.x + threadIdx.x; i < cnt; i += stride) {
        int e = act[i];
        int a = ei[e], b = ei[NE + e];
        best[a] = ~0ull; best[b] = ~0ull;
        bool live = !(used[a] | used[b]);
        u64 mask = __ballot(live);
        if (mask) {
            int lane = threadIdx.x & 63;
            int leader = __ffsll((unsigned long long)mask) - 1;
            int base = 0;
            if (lane == leader) base = atomicAdd(ncntp, __popcll(mask));
            base = __shfl(base, leader, 64);
            if (live) nxt[base + __popcll(mask & ((1ull << lane) - 1ull))] = e;
        }
    }
}
__global__ void mk_min(const u64* __restrict__ key, const int* __restrict__ ei,
                       const int* __restrict__ act, const int* __restrict__ cntp,
                       u64* best) {
    int cnt = cntp[0];
    int stride = gridDim.x * blockDim.x;
    for (int i = blockIdx.x * blockDim.x + threadIdx.x; i < cnt; i += stride) {
        int e = act[i];
        u64 k = key[e];
        atomicMin(&best[ei[e]], k);
        atomicMin(&best[ei[NE + e]], k);
    }
}
__global__ void __launch_bounds__(1024) match_fin(
        const u64* __restrict__ key, const int* __restrict__ ei,
        int* sel, u64* best, u32* used,
        int* listA, int* listB, const int* __restrict__ cntp) {
    int tid = threadIdx.x;
    int cnt = cntp[0];
    int* cur = listA; int* nxt = listB;
    __shared__ int s_n;
    for (int round = 0; round < 4096 && cnt > 0; ++round) {
        for (int i = tid; i < cnt; i += 1024) {
            int e = cur[i]; u64 k = key[e];
            atomicMin(&best[ei[e]], k);
            atomicMin(&best[ei[NE + e]], k);
        }
        __syncthreads();
        for (int i = tid; i < cnt; i += 1024) {
            int e = cur[i]; u64 k = key[e];
            int a = ei[e], b = ei[NE + e];
            if (best[a] == k && best[b] == k) { sel[e] = 1; used[a] = 1u; used[b] = 1u; }
        }
        if (tid == 0) s_n = 0;
        __syncthreads();
        for (int i = tid; i < cnt; i += 1024) {
            int e = cur[i];
            int a = ei[e], b = ei[NE + e];
            best[a] = ~0ull; best[b] = ~0ull;
            if (!(used[a] | used[b])) {
                int idx = atomicAdd(&s_n, 1);
                nxt[idx] = e;
            }
        }
        __syncthreads();
        cnt = s_n;
        int* t = cur; cur = nxt; nxt = t;
        __syncthreads();
    }
}

// apply_sel + ht init + cin zero (grid = NE/256; KEY dead here)
__global__ void apply_sel(const int* __restrict__ ei, const int* __restrict__ sel,
                          const float* __restrict__ score,
                          int* cluster, int* other, float* nscore,
                          u32* ht, u32* cin) {
    int e = blockIdx.x * 256 + threadIdx.x;
    ht[e << 1] = 0xFFFFFFFFu;
    ht[(e << 1) + 1] = 0xFFFFFFFFu;
    if (e < NN) cin[e] = 0u;
    if (sel[e] != 1) return;
    int u = ei[e], v = ei[NE + e];
    int rep = min(u, v);
    cluster[u] = rep; cluster[v] = rep;
    if (u != v) other[rep] = u + v - rep;
    nscore[rep] = score[e];
}

// ---------------- coarse graph: dedup (cu,cv) pairs via hash set ----------------
__global__ void coarse_build(const int* __restrict__ ei, const int* __restrict__ cluster,
                             u32* ht, int* misc, int* ce_u, int* ce_v, u32* deg,
                             u32* cin) {
    int e = blockIdx.x * 256 + threadIdx.x;
    if (e >= NE) return;
    int cu = cluster[ei[e]], cv = cluster[ei[NE + e]];
    if (cu == cv) return;
    u32 k = (u32)cu * 32768u + (u32)cv;
    u32 h = ((k * 2654435761u) >> 12) & HTM;
    while (true) {
        u32 old = atomicCAS(&ht[h], 0xFFFFFFFFu, k);
        if (old == 0xFFFFFFFFu) {
            int idx = atomicAdd(&misc[0], 1);
            ce_u[idx] = cu; ce_v[idx] = cv;
            atomicAdd(&deg[cu], 1u);
            atomicAdd(&cin[cv], 1u);
            break;
        }
        if (old == k) break;
        h = (h + 1) & HTM;
    }
}
// dis + readout-scratch zero + gcnt (per-wave ballot reduction; batch sorted)
__global__ void dis_kernel(const u32* __restrict__ deg, float* dis,
                           float* racc1, float* racc2,
                           const int* __restrict__ clus, const int* __restrict__ batch,
                           float* gcnt) {
    int n = blockIdx.x * 256 + threadIdx.x;
    if (n >= NN) return;
    u32 d = deg[n];
    dis[n] = d ? (float)(1.0 / sqrt((double)d)) : 0.0f;
    if (n < 4096) racc1[n] = 0.0f;
    if (n < 2048) racc2[n] = 0.0f;
    bool val = (clus[n] == n);
    int bt = batch[n];
    int lane = threadIdx.x & 63;
    #pragma unroll
    for (int g = 0; g < 8; ++g) {
        u64 m = __ballot(val && bt == g);
        if (m && lane == (__ffsll((unsigned long long)m) - 1))
            unsafeAtomicAdd(&gcnt[g], (float)__popcll(m));
    }
}

// ---------------- multi-block CSR/compaction scan (3 kernels) ----------------
// pass 1: per-256-elem block sums of cin and valid
__global__ void __launch_bounds__(256) scan_part(const u32* __restrict__ cin,
                                                 const int* __restrict__ clus,
                                                 int* __restrict__ bsum) {
    int t = threadIdx.x;
    int i = blockIdx.x * 256 + t;
    int vc = (int)cin[i];
    int vv = (clus[i] == i) ? 1 : 0;
    #pragma unroll
    for (int off = 32; off > 0; off >>= 1) {
        vc += __shfl_down(vc, off, 64);
        vv += __shfl_down(vv, off, 64);
    }
    __shared__ int sc[4], sv[4];
    if ((t & 63) == 0) { sc[t >> 6] = vc; sv[t >> 6] = vv; }
    __syncthreads();
    if (t == 0) {
        bsum[blockIdx.x] = sc[0] + sc[1] + sc[2] + sc[3];
        bsum[128 + blockIdx.x] = sv[0] + sv[1] + sv[2] + sv[3];
    }
}
// pass 2: exclusive scan of the 128 block sums (both arrays); misc[4] = total valid
__global__ void __launch_bounds__(128) scan_mid(const int* __restrict__ bsum,
                                                int* __restrict__ boff, int* misc) {
    __shared__ int s[256];
    int t = threadIdx.x;
    int v0 = bsum[t], v1 = bsum[128 + t];
    s[t] = v0; s[128 + t] = v1;
    __syncthreads();
    for (int d = 1; d < 128; d <<= 1) {
        int a = (t >= d) ? s[t - d] : 0;
        int b = (t >= d) ? s[128 + t - d] : 0;
        __syncthreads();
        if (t >= d) { s[t] += a; s[128 + t] += b; }
        __syncthreads();
    }
    boff[t] = s[t] - v0;            // exclusive
    boff[128 + t] = s[128 + t] - v1;
    if (t == 127) misc[4] = s[255];
}
// pass 3: intra-block exclusive scan (packed (cin<<9)|valid; per-block valid sum
// <= 256 < 512 so the 9-bit field never overflows) + block offset + final writes
__global__ void __launch_bounds__(256) scan_fin(const u32* __restrict__ cin,
                                                const int* __restrict__ clus,
                                                const int* __restrict__ boff,
                                                int* off, int* cur, int* cidx, int* perm) {
    __shared__ int s[256];
    int t = threadIdx.x;
    int i = blockIdx.x * 256 + t;
    int vc = (int)cin[i];
    int vv = (clus[i] == i) ? 1 : 0;
    int p = (vc << 9) | vv;
    s[t] = p;
    __syncthreads();
    for (int d = 1; d < 256; d <<= 1) {
        int a = (t >= d) ? s[t - d] : 0;
        __syncthreads();
        if (t >= d) s[t] += a;
        __syncthreads();
    }
    int ex = s[t] - p;   // exclusive packed prefix
    int o = boff[blockIdx.x] + (ex >> 9);
    off[i] = o; cur[i] = o;
    int c = boff[128 + blockIdx.x] + (ex & 511);
    cidx[i] = c;
    if (vv) perm[c] = i;
}

// csr_a stores COMPACT source row indices (cidx available: scan runs first)
__global__ void csr_scatter(const int* __restrict__ ce_u, const int* __restrict__ ce_v,
                            const float* __restrict__ dis, const int* __restrict__ misc,
                            int* cur, int* csr_a, float* csr_c,
                            const int* __restrict__ cidx) {
    int e = blockIdx.x * 256 + threadIdx.x;
    if (e >= misc[0]) return;
    int a = ce_u[e], b = ce_v[e];
    int pos = atomicAdd(&cur[b], 1);
    csr_a[pos] = cidx[a];
    csr_c[pos] = -dis[a] * dis[b];
}

// ---- packed fragment index: row r, col k -> ushort offset ----
__device__ __forceinline__ size_t pk_idx(int r, int k, int KT) {
    return ((((size_t)(r >> 4) * KT + (k >> 5)) << 6) + (((k >> 3) & 3) << 4) + (r & 15)) << 3;
}

// ---------------- fused: packed Ax gather (COMPACT rows, LDS-staged coalesced) ----------------
__global__ void __launch_bounds__(256) conv_all(
        const float* __restrict__ x, const int* __restrict__ perm,
        const int* __restrict__ misc,
        const int* __restrict__ other, const float* __restrict__ nsc,
        unsigned short* __restrict__ Abf, float* __restrict__ pxl,
        const float* __restrict__ B10, const float* __restrict__ B11,
        unsigned short* __restrict__ Bp1,
        const float* __restrict__ B20, const float* __restrict__ B21,
        unsigned short* __restrict__ Bp2) {
    int bid = blockIdx.x;
    int t = threadIdx.x;
    if (bid < 2048) {   // A-tile gather via coalesced row staging in LDS
        __shared__ unsigned short S[16][1032];   // +8 ushort pad: 2-way max bank alias
        __shared__ int Srow[16], So[16];
        __shared__ float Ss[16];
        int cnt = misc[4];
        int tile = bid;
        if ((tile << 4) >= ((cnt + 127) & ~127)) return;  // beyond padded M': unread
        if (t < 16) {
            int ci = (tile << 4) + t;
            bool val = ci < cnt;
            int row = val ? perm[ci] : -1;
            Srow[t] = row;
            So[t] = val ? other[row] : -1;
            Ss[t] = val ? nsc[row] : 0.0f;
        }
        __syncthreads();
        if (t < 16) {   // pxl (col 1024), 16 scattered scalar loads — tiny
            int row = Srow[t];
            float v = 0.0f;
            if (row >= 0) {
                int o = So[t];
                v = x[(size_t)row * FIN + 1024];
                if (o >= 0) v += x[(size_t)o * FIN + 1024];
                v *= Ss[t];
            }
            pxl[(tile << 4) + t] = v;
        }
        // stage 16 rows: lane t reads cols t, t+256, t+512, t+768 — fully coalesced,
        // all loads independent across k and r (deep MLP)
        for (int r = 0; r < 16; ++r) {
            int row = Srow[r];          // wave-uniform
            int o = So[r];
            float s = Ss[r];
            if (row >= 0) {
                const float* xr = x + (size_t)row * FIN;
                const float* xo = x + (size_t)(o >= 0 ? o : row) * FIN;
                #pragma unroll
                for (int k = 0; k < 4; ++k) {
                    int c = (k << 8) + t;
                    float v = xr[c];
                    if (o >= 0) v += xo[c];
                    S[r][c] = f2bf(v * s);
                }
            } else {
                #pragma unroll
                for (int k = 0; k < 4; ++k) S[r][(k << 8) + t] = 0;
            }
        }
        __syncthreads();
        // pack: 16B LDS reads -> 16B global stores (identical layout/content as before)
        int wave = t >> 6, lane = t & 63;
        int l16 = lane & 15, quad = lane >> 4;
        #pragma unroll
        for (int kt0 = 0; kt0 < 8; ++kt0) {
            int kt = (kt0 << 2) + wave;
            int c0 = (kt << 5) + (quad << 3);
            us8 v = *(const us8*)&S[l16][c0];
            *(us8*)&Abf[((((size_t)tile << 5) + kt) << 9) + ((size_t)lane << 3)] = v;
        }
    } else if (bid < 2560) {   // L1 weight transpose, KT=32
        int j = bid - 2048;
        int n = ((j & 3) << 8) + t;
        int k0 = (j >> 2) << 3;
        unsigned short h[8];
        #pragma unroll
        for (int jj = 0; jj < 8; ++jj) {
            int k = k0 + jj;
            float v = (n < 512) ? B10[(size_t)k * 512 + n] : B11[(size_t)k * 512 + (n - 512)];
            h[jj] = f2bf(v);
        }
        *(us8*)&Bp1[pk_idx(n, k0, 32)] = *(const us8*)h;
    } else {                   // L2 weight transpose, KT=16
        int j = bid - 2560;
        int n = ((j & 3) << 8) + t;
        int k0 = (j >> 2) << 3;
        unsigned short h[8];
        #pragma unroll
        for (int jj = 0; jj < 8; ++jj) {
            int k = k0 + jj;
            float v = (n < 512) ? B20[(size_t)k * 512 + n] : B21[(size_t)k * 512 + (n - 512)];
            h[jj] = f2bf(v);
        }
        *(us8*)&Bp2[pk_idx(n, k0, 16)] = *(const us8*)h;
    }
}

// ---------------- packed-fragment bf16 MFMA GEMM with LDS DMA double-buffer ----------------
// BM=64 x BN=128 tiles (finer M): ~2256 active blocks halve per-block time so the
// 1024-slot co-residency quantization costs 1.5T instead of 2T. Splitting M (not N)
// keeps A-panel reuse unchanged; only the 2 MB L2-resident B is re-read more.
// 12 LDS fragments (4 A + 8 B) = 24 KB double-buffered; 3 dma16/wave; each wave
// computes 32x64 via acc[4][2] (transposed D^T form, direct float4/us4 stores).
template <bool R1>
__global__ void __launch_bounds__(256, 4) gemm_pk(
        const unsigned short* __restrict__ Ap, const unsigned short* __restrict__ Bp,
        float* __restrict__ P, unsigned short* __restrict__ Pb, int KT,
        const float* __restrict__ pxl, const float* __restrict__ w0,
        const float* __restrict__ w1, const int* __restrict__ msc) {
    __shared__ unsigned short L[2][6144];
    int tid = threadIdx.x;
    int bid = blockIdx.x;
    int bn = (bid & 7) << 7;
    int bm = (bid >> 3) << 6;                    // BM=64; dead blocks = contiguous tail
    if (bm >= ((msc[4] + 127) & ~127)) return;   // zero-row block: output never read
    int wave = tid >> 6, lane = tid & 63, quad = lane >> 4, l16 = lane & 15;
    int moff = (wave >> 1) << 5, noff = (wave & 1) << 6;   // wave: 32 M x 64 N
    f32x4 acc[4][2];   // [ni][mi] — transposed-output fragments
    #pragma unroll
    for (int i = 0; i < 4; ++i)
        #pragma unroll
        for (int j = 0; j < 2; ++j) acc[i][j] = (f32x4){0.f, 0.f, 0.f, 0.f};

    const unsigned short* src[3];
    unsigned short* dst[3];
    #pragma unroll
    for (int q = 0; q < 3; ++q) {
        int f = wave * 3 + q;                    // 12 frags: 0..3 = A, 4..11 = B
        int tg = (f < 4) ? ((bm >> 4) + f) : ((bn >> 4) + (f - 4));
        src[q] = ((f < 4) ? Ap : Bp) + (((size_t)tg * KT) << 9) + ((size_t)lane << 3);
        dst[q] = &L[0][(size_t)f << 9];
    }
    const unsigned short* ra = &L[0][(size_t)((wave >> 1) << 1) << 9];      // A frags 2*(w>>1)..+1
    const unsigned short* rb = &L[0][(size_t)(4 + ((wave & 1) << 2)) << 9]; // B frags 4+(w&1)*4..+3

    #pragma unroll
    for (int q = 0; q < 3; ++q) dma16(dst[q], src[q]);
    __syncthreads();

    int cur = 0;
    for (int kt = 0; kt < KT; ++kt) {
        if (kt + 1 < KT) {
            int nb = (cur ^ 1) * 6144;
            size_t go = ((size_t)(kt + 1)) << 9;
            #pragma unroll
            for (int q = 0; q < 3; ++q) dma16(dst[q] + nb, src[q] + go);
        }
        const unsigned short* la = ra + cur * 6144;
        const unsigned short* lb = rb + cur * 6144;
        bf16x8 af[2], bf[4];
        #pragma unroll
        for (int i = 0; i < 2; ++i) af[i] = ld_frag(la + ((size_t)i << 9) + (lane << 3));
        #pragma unroll
        for (int i = 0; i < 4; ++i) bf[i] = ld_frag(lb + ((size_t)i << 9) + (lane << 3));
        #pragma unroll
        for (int ni = 0; ni < 4; ++ni)
            #pragma unroll
            for (int mi = 0; mi < 2; ++mi)
                acc[ni][mi] = __builtin_amdgcn_mfma_f32_16x16x32_bf16(bf[ni], af[mi], acc[ni][mi], 0, 0, 0);
        __syncthreads();
        cur ^= 1;
    }
    // ---- epilogue: D^T: n = bn+noff+ni*16+quad*4+r2, m = bm+moff+mi*16+l16 ----
    #pragma unroll
    for (int mi = 0; mi < 2; ++mi) {
        int m = bm + moff + (mi << 4) + l16;
        float pm = 0.0f;
        if (R1) pm = pxl[m];
        #pragma unroll
        for (int ni = 0; ni < 4; ++ni) {
            int n0 = bn + noff + (ni << 4) + (quad << 2);
            float v0 = acc[ni][mi][0], v1 = acc[ni][mi][1];
            float v2 = acc[ni][mi][2], v3 = acc[ni][mi][3];
            if (bn < 512) {
                if (R1) {
                    float4 wv = *(const float4*)&w0[524288 + n0];
                    v0 += pm * wv.x; v1 += pm * wv.y; v2 += pm * wv.z; v3 += pm * wv.w;
                }
                *(float4*)&P[(size_t)m * 512 + n0] = make_float4(v0, v1, v2, v3);
            } else {
                if (R1) {
                    float4 wv = *(const float4*)&w1[524288 + n0 - 512];
                    v0 += pm * wv.x; v1 += pm * wv.y; v2 += pm * wv.z; v3 += pm * wv.w;
                }
                unsigned short h[4] = {f2bf(v0), f2bf(v1), f2bf(v2), f2bf(v3)};
                *(us4*)&Pb[(size_t)m * 512 + (n0 - 512)] = *(const us4*)h;
            }
        }
    }
}

// ---------------- fused gather + BN + ReLU: one wave per COMPACT destination row ----------------
template <bool BF16OUT>
__global__ void __launch_bounds__(256) cheb_fuse(
        const float* __restrict__ P, const unsigned short* __restrict__ Pb,
        const int* __restrict__ off,
        const int* __restrict__ csr_a, const float* __restrict__ csr_c,
        const int* __restrict__ misc, const float* __restrict__ bias,
        const float* __restrict__ bn, float* __restrict__ Hf,
        unsigned short* __restrict__ Hb, const int* __restrict__ perm) {
    int b = (blockIdx.x * 256 + threadIdx.x) >> 6;
    int lane = threadIdx.x & 63;
    if (b >= misc[4]) return;
    int r = perm[b];
    int s = off[r];
    int e = (r < NN - 1) ? off[r + 1] : misc[0];
    int c0 = lane << 3;
    float a0[4], a1[4];
    {
        float4 t0 = *(const float4*)&P[(size_t)b * 512 + c0];
        float4 t1 = *(const float4*)&P[(size_t)b * 512 + c0 + 4];
        a0[0] = t0.x; a0[1] = t0.y; a0[2] = t0.z; a0[3] = t0.w;
        a1[0] = t1.x; a1[1] = t1.y; a1[2] = t1.z; a1[3] = t1.w;
    }
    for (int j = s; j < e; ++j) {
        int a = csr_a[j];          // already a compact row index
        float cf = csr_c[j];
        us8 raw = *(const us8*)&Pb[(size_t)a * 512 + c0];
        a0[0] = fmaf(cf, bf2f(raw[0]), a0[0]); a0[1] = fmaf(cf, bf2f(raw[1]), a0[1]);
        a0[2] = fmaf(cf, bf2f(raw[2]), a0[2]); a0[3] = fmaf(cf, bf2f(raw[3]), a0[3]);
        a1[0] = fmaf(cf, bf2f(raw[4]), a1[0]); a1[1] = fmaf(cf, bf2f(raw[5]), a1[1]);
        a1[2] = fmaf(cf, bf2f(raw[6]), a1[2]); a1[3] = fmaf(cf, bf2f(raw[7]), a1[3]);
    }
    float o[8];
    #pragma unroll
    for (int i = 0; i < 8; ++i) {
        int j = c0 + i;
        float acc = (i < 4) ? a0[i] : a1[i - 4];
        float ga = bn[j], be = bn[512 + j], mn = bn[1024 + j], vr = bn[1536 + j];
        float sc = (float)(1.0 / sqrt((double)vr + 1e-5));
        float v = (acc + bias[j] - mn) * sc * ga + be;
        o[i] = v > 0.0f ? v : 0.0f;
    }
    if (BF16OUT) {
        unsigned short h[8];
        #pragma unroll
        for (int i = 0; i < 8; ++i) h[i] = f2bf(o[i]);
        *(us8*)&Hb[pk_idx(b, c0, 16)] = *(const us8*)h;   // packed for layer-2 GEMM
    } else {
        *(float4*)&Hf[(size_t)b * 512 + c0] = make_float4(o[0], o[1], o[2], o[3]);
        *(float4*)&Hf[(size_t)b * 512 + c0 + 4] = make_float4(o[4], o[5], o[6], o[7]);
    }
}

// ---------------- global max+mean pool over valid nodes per graph ----------------
// H rows are compact; gather via cidx[n] (monotone over n -> stays coalesced).
// 2048 blocks x 16 nodes: 8 blocks/CU (vs 2 at 64-node chunks) — latency-bound fix.
__global__ void __launch_bounds__(256) pool_kernel(
        const float* __restrict__ H, const int* __restrict__ cluster,
        const int* __restrict__ batch, u32* gmaxb, float* gsum,
        const int* __restrict__ cidx) {
    int t = threadIdx.x;
    int n0 = blockIdx.x * 16;
    float m0 = 0.0f, m1 = 0.0f, s0 = 0.0f, s1 = 0.0f;
    int cur = batch[n0];
    for (int i = 0; i < 16; ++i) {
        int n = n0 + i;
        int bt = batch[n];
        if (bt != cur) {
            atomicMax(&gmaxb[cur * 512 + t], __float_as_uint(m0));
            atomicMax(&gmaxb[cur * 512 + t + 256], __float_as_uint(m1));
            unsafeAtomicAdd(&gsum[cur * 512 + t], s0);
            unsafeAtomicAdd(&gsum[cur * 512 + t + 256], s1);
            m0 = m1 = s0 = s1 = 0.0f; cur = bt;
        }
        if (cluster[n] == n) {
            size_t ci = (size_t)cidx[n];
            float h0 = H[ci * 512 + t];
            float h1 = H[ci * 512 + t + 256];
            m0 = fmaxf(m0, h0); m1 = fmaxf(m1, h1);
            s0 += h0; s1 += h1;
        }
    }
    atomicMax(&gmaxb[cur * 512 + t], __float_as_uint(m0));
    atomicMax(&gmaxb[cur * 512 + t + 256], __float_as_uint(m1));
    unsafeAtomicAdd(&gsum[cur * 512 + t], s0);
    unsafeAtomicAdd(&gsum[cur * 512 + t + 256], s1);
}

// ---------------- parallel readout MLP (3 kernels) ----------------
__global__ void __launch_bounds__(512) ro1(
        const u32* __restrict__ gmaxb, const float* __restrict__ gsum,
        const float* __restrict__ gcnt, const float* __restrict__ l1w,
        float* __restrict__ racc1) {
    int o = threadIdx.x;
    int k0 = blockIdx.x << 4;
    float acc[8] = {0, 0, 0, 0, 0, 0, 0, 0};
    float inv[8];
    #pragma unroll
    for (int b = 0; b < 8; ++b) inv[b] = 1.0f / fmaxf(gcnt[b], 1.0f);
    for (int kk = 0; kk < 16; ++kk) {
        int k = k0 + kk;
        float w = l1w[(size_t)k * 512 + o];
        #pragma unroll
        for (int b = 0; b < 8; ++b) {
            float g = (k < 512) ? __uint_as_float(gmaxb[b * 512 + k])
                                : gsum[b * 512 + (k - 512)] * inv[b];
            acc[b] = fmaf(g, w, acc[b]);
        }
    }
    #pragma unroll
    for (int b = 0; b < 8; ++b) unsafeAtomicAdd(&racc1[b * 512 + o], acc[b]);
}
// ro3: layer-2 partials with ro2's BN inlined (recomputed per k-slice)
__global__ void __launch_bounds__(256) ro3(
        const float* __restrict__ racc1, const float* __restrict__ l1b,
        const float* __restrict__ bn3, const float* __restrict__ l2w,
        float* __restrict__ racc2) {
    int o = threadIdx.x;
    int k0 = blockIdx.x << 4;
    float acc[8] = {0, 0, 0, 0, 0, 0, 0, 0};
    for (int kk = 0; kk < 16; ++kk) {
        int k = k0 + kk;
        float ga = bn3[k], be = bn3[512 + k], mn = bn3[1024 + k], vr = bn3[1536 + k];
        float sc = (float)(1.0 / sqrt((double)vr + 1e-5));
        float bi = l1b[k];
        float w = l2w[(size_t)k * 256 + o];
        #pragma unroll
        for (int b = 0; b < 8; ++b) {
            float g1 = (racc1[b * 512 + k] + bi - mn) * sc * ga + be;
            g1 = g1 > 0.0f ? g1 : 0.0f;
            acc[b] = fmaf(g1, w, acc[b]);
        }
    }
    #pragma unroll
    for (int b = 0; b < 8; ++b) unsafeAtomicAdd(&racc2[b * 256 + o], acc[b]);
}
__global__ void __launch_bounds__(256) ro4(
        const float* __restrict__ racc2, const float* __restrict__ l2b,
        const float* __restrict__ bn4, const float* __restrict__ l3w,
        const float* __restrict__ l3b, float* __restrict__ out) {
    __shared__ float G2[8 * 256];
    int o = threadIdx.x;
    {
        float ga = bn4[o], be = bn4[256 + o], mn = bn4[512 + o], vr = bn4[768 + o];
        float sc = (float)(1.0 / sqrt((double)vr + 1e-5));
        float bi = l2b[o];
        #pragma unroll
        for (int b = 0; b < 8; ++b) {
            float v = (racc2[b * 256 + o] + bi - mn) * sc * ga + be;
            v = v > 0.0f ? v : 0.0f;
            G2[b * 256 + o] = v;
            out[32 + b * 256 + o] = v;
        }
    }
    __syncthreads();
    if (o < 8) {
        int b = o;
        float r[4];
        #pragma unroll
        for (int c = 0; c < 4; ++c) {
            float acc = l3b[c];
            for (int k = 0; k < 256; ++k) acc += G2[b * 256 + k] * l3w[k * 4 + c];
            r[c] = acc > 0.0f ? acc : 0.0f;
        }
        float mx = fmaxf(fmaxf(r[0], r[1]), fmaxf(r[2], r[3]));
        float s = 0.0f;
        #pragma unroll
        for (int c = 0; c < 4; ++c) s += expf(r[c] - mx);
        float lse = mx + logf(s);
        #pragma unroll
        for (int c = 0; c < 4; ++c) out[b * 4 + c] = r[c] - lse;
    }
}

extern "C" void kernel_launch(void* const* d_in, const int* in_sizes, int n_in,
                              void* d_out, int out_size, void* d_ws, size_t ws_size,
                              hipStream_t stream) {
    const float* x      = (const float*)d_in[0];
    const int*   ei     = (const int*)d_in[1];
    const int*   batch  = (const int*)d_in[2];
    const float* pool_w = (const float*)d_in[3];
    const float* pool_b = (const float*)d_in[4];
    const float* c1_w0  = (const float*)d_in[5];
    const float* c1_w1  = (const float*)d_in[6];
    const float* c1_b   = (const float*)d_in[7];
    const float* c2_w0  = (const float*)d_in[8];
    const float* c2_w1  = (const float*)d_in[9];
    const float* c2_b   = (const float*)d_in[10];
    const float* bn1    = (const float*)d_in[11];
    const float* bn2    = (const float*)d_in[12];
    const float* bn3    = (const float*)d_in[13];
    const float* bn4    = (const float*)d_in[14];
    const float* l1w    = (const float*)d_in[15];
    const float* l1b    = (const float*)d_in[16];
    const float* l2w    = (const float*)d_in[17];
    const float* l2b    = (const float*)d_in[18];
    const float* l3w    = (const float*)d_in[19];
    const float* l3b    = (const float*)d_in[20];
    float* out = (float*)d_out;
    char* ws = (char*)d_ws;

    double* a_d   = (double*)(ws + WS_A_D);
    double* b_d   = (double*)(ws + WS_B_D);
    u32*    emax  = (u32*)(ws + WS_EMAX);
    double* ssum  = (double*)(ws + WS_SSUM);
    double* exd   = (double*)(ws + WS_EXD);
    u32*    cin   = (u32*)(ws + WS_CIN);
    int*    cidxp = (int*)(ws + WS_CIDX);
    int*    permp = (int*)(ws + WS_PERM);
    int*    bsum  = (int*)(ws + WS_BSUM);
    int*    boffp = (int*)(ws + WS_BOFF);
    u64*    key   = (u64*)(ws + WS_KEY);
    u64*    best  = (u64*)(ws + WS_BEST);
    u32*    used  = (u32*)(ws + WS_USED);
    int*    curp  = (int*)(ws + WS_CUR);
    int*    act0  = (int*)(ws + WS_ACT0);
    int*    act1  = (int*)(ws + WS_ACT1);
    unsigned short* bthi = (unsigned short*)(ws + WS_BTHI);
    unsigned short* bt2  = (unsigned short*)(ws + WS_BT2);
    float*  pxl   = (float*)(ws + WS_PXL);
    u32*    ht    = (u32*)(ws + WS_HT);
    float*  racc1 = (float*)(ws + WS_RACC1);
    float*  racc2 = (float*)(ws + WS_RACC2);
    float*  score = (float*)(ws + WS_SCORE);
    int*    csr_a = (int*)(ws + WS_CSRA);
    int*    sel   = (int*)(ws + WS_SEL);
    float*  csr_c = (float*)(ws + WS_CSRC);
    int*    clus  = (int*)(ws + WS_CLUST);
    int*    other = (int*)(ws + WS_OTHER);
    float*  nsc   = (float*)(ws + WS_NSC);
    int*    ce_u  = (int*)(ws + WS_CEU);
    int*    ce_v  = (int*)(ws + WS_CEV);
    u32*    deg   = (u32*)(ws + WS_DEG);
    int*    off   = (int*)(ws + WS_OFF);
    float*  dis   = (float*)(ws + WS_DIS);
    int*    misc  = (int*)(ws + WS_MISC);
    u32*    gmaxb = (u32*)(ws + WS_GMAX);
    float*  gsum  = (float*)(ws + WS_GSUM);
    float*  gcnt  = (float*)(ws + WS_GCNT);
    float*  P     = (float*)(ws + WS_P);
    unsigned short* Pb = (unsigned short*)(ws + WS_PB);
    unsigned short* ax = (unsigned short*)(ws + WS_H);   // packed Ax bf16 (gemm1 A)
    unsigned short* hb = (unsigned short*)(ws + WS_H);   // packed Hb bf16 (gemm2 A)
    float*  H     = (float*)(ws + WS_H);                 // final H fp32

    // ---- phase A: scores, matching, coarse graph ----
    node_dots<<<NN / 4, 256, 0, stream>>>(x, pool_w, a_d, b_d,
                                          emax, ssum, deg, misc, gmaxb, gsum, gcnt,
                                          best, used, clus, other, nsc);
    edge_p1<<<NE / 256, 256, 0, stream>>>(ei, a_d, b_d, pool_b, exd, emax);
    edge_p2<<<NE / 256, 256, 0, stream>>>(ei, exd, emax, ssum);
    edge_p3<<<NE / 256, 256, 0, stream>>>(ei, exd, ssum, score, key, sel, act0, best);

    {
        static const int gr[5] = {512, 512, 256, 128, 64};
        int* acts[2] = {act0, act1};
        for (int r = 0; r < 4; ++r) {
            int c = r & 1, n = 1 - c;
            mk_sel<<<gr[r], 256, 0, stream>>>(key, ei, acts[c], &misc[1 + c],
                                              &misc[1 + n], best, used, sel);
            mk_compact<<<gr[r], 256, 0, stream>>>(ei, acts[c], &misc[1 + c],
                                                  acts[n], &misc[1 + n], best, used);
            mk_min<<<gr[r + 1], 256, 0, stream>>>(key, ei, acts[n], &misc[1 + n], best);
        }
        match_fin<<<1, 1024, 0, stream>>>(key, ei, sel, best, used,
                                          act0, act1, &misc[1]);
    }

    apply_sel<<<NE / 256, 256, 0, stream>>>(ei, sel, score, clus, other, nsc, ht, cin);
    coarse_build<<<NE / 256, 256, 0, stream>>>(ei, clus, ht, misc, ce_u, ce_v, deg, cin);
    dis_kernel<<<NN / 256, 256, 0, stream>>>(deg, dis, racc1, racc2, clus, batch, gcnt);
    scan_part<<<128, 256, 0, stream>>>(cin, clus, bsum);
    scan_mid<<<1, 128, 0, stream>>>(bsum, boffp, misc);
    scan_fin<<<128, 256, 0, stream>>>(cin, clus, boffp, off, curp, cidxp, permp);
    csr_scatter<<<NE / 256, 256, 0, stream>>>(ce_u, ce_v, dis, misc, curp, csr_a, csr_c,
                                              cidxp);

    // ---- phase B: ChebConv layers on COMPACT rows (misc[4] ~ 0.55*NN survive) ----
    conv_all<<<2816, 256, 0, stream>>>(x, permp, misc, other, nsc, ax, pxl,
                                       c1_w0, c1_w1, bthi, c2_w0, c2_w1, bt2);
    gemm_pk<true><<<4096, 256, 0, stream>>>(ax, bthi, P, Pb, 32, pxl, c1_w0, c1_w1, misc);
    cheb_fuse<true><<<NN / 4, 256, 0, stream>>>(P, Pb, off, csr_a, csr_c, misc, c1_b, bn1,
                                                nullptr, hb, permp);

    gemm_pk<false><<<4096, 256, 0, stream>>>(hb, bt2, P, Pb, 16, nullptr, nullptr, nullptr,
                                             misc);
    cheb_fuse<false><<<NN / 4, 256, 0, stream>>>(P, Pb, off, csr_a, csr_c, misc, c2_b, bn2,
                                                 H, nullptr, permp);

    pool_kernel<<<NN / 16, 256, 0, stream>>>(H, clus, batch, gmaxb, gsum, cidxp);

    // ---- parallel readout ----
    ro1<<<64, 512, 0, stream>>>(gmaxb, gsum, gcnt, l1w, racc1);
    ro3<<<32, 256, 0, stream>>>(racc1, l1b, bn3, l2w, racc2);
    ro4<<<1, 256, 0, stream>>>(racc2, l2b, bn4, l3w, l3b, out);
}

// Round 13
// 695.878 us; speedup vs baseline: 1.1435x; 1.0224x over previous
//
#include <hip/hip_runtime.h>
#include <hip/hip_bf16.h>
#include <cstdint>
#include <cmath>

typedef unsigned int u32;
typedef unsigned long long u64;
typedef float f32x4 __attribute__((ext_vector_type(4)));
typedef __bf16 bf16x8 __attribute__((ext_vector_type(8)));
typedef unsigned short us8 __attribute__((ext_vector_type(8)));
typedef unsigned short us4 __attribute__((ext_vector_type(4)));

#define NN 32768
#define NE 131072
#define FIN 1025
#define HTS 262144
#define HTM (HTS - 1)

// ---------------- workspace layout (byte offsets) ----------------
#define WS_A_D    0ul          // double[NN]
#define WS_B_D    262144ul     // double[NN]
#define WS_EMAX   524288ul     // u32[NN]
#define WS_SSUM   655360ul     // double[NN]
#define WS_EXD    917504ul     // double[NE]
#define WS_CIN    917504ul     // u32[NN]  overlays EXD head (zeroed in apply_sel)
#define WS_KEY    1966080ul    // u64[NE]
#define WS_BEST   3014656ul    // u64[NN]
#define WS_USED   3276800ul    // u32[NN]
#define WS_CUR    3276800ul    // int[NN]  overlays USED (dead after match_fin)
#define WS_ACT0   3407872ul    // int[NE]
#define WS_ACT1   3932160ul    // int[NE]   (zone ends 4456448)
#define WS_BTHI   0ul          // ushort[1024*1024] packed L1 weights (phase B, 0..2097152)
#define WS_BT2    3407872ul    // ushort[1024*512] packed L2 weights (overlays ACT0/1)
#define WS_HT     1966080ul    // u32[HTS] overlays KEY (init in apply_sel, dead after coarse_build)
// readout scratch (phase B, overlays dead KEY tail):
#define WS_RACC1  2097152ul    // float[8*512]   (..2113536)
#define WS_RACC2  2113536ul    // float[8*256]   (..2121728)
// compaction maps: overlay dead HT/KEY tail, AFTER racc2, clear of BTHI (2097152+)
#define WS_CIDX   2129920ul    // int[NN]  node->compact  (..2260992)
#define WS_PERM   2260992ul    // int[NN]  compact->node  (..2392064)
#define WS_BSUM   2392064ul    // int[256] scan block sums (..2393088)
#define WS_BOFF   2393088ul    // int[256] scan block offsets (..2394112, < 3014656 OK)
// persistent:
#define WS_SCORE  4456448ul    // float[NE]
#define WS_CSRA   4456448ul    // int[NE]  overlays SCORE (dead after apply_sel)
#define WS_SEL    4980736ul    // int[NE]
#define WS_CSRC   4980736ul    // float[NE] overlays SEL (dead after apply_sel)
#define WS_CLUST  5505024ul    // int[NN]
#define WS_OTHER  5636096ul    // int[NN]
#define WS_NSC    5767168ul    // float[NN]
#define WS_CEU    5898240ul    // int[NE]
#define WS_CEV    6422528ul    // int[NE]
#define WS_DEG    6946816ul    // u32[NN]
#define WS_OFF    6946816ul    // int[NN]  overlays DEG
#define WS_DIS    7077888ul    // float[NN]
#define WS_PXL    7077888ul    // float[NN] overlays DIS (dis dead after csr_scatter)
#define WS_MISC   7208960ul    // int[64]
#define WS_GMAX   7209216ul    // u32[8*512]
#define WS_GSUM   7225600ul    // float[8*512]
#define WS_GCNT   7241984ul    // float[64]
#define WS_P      7242240ul    // float[NN*512] P0 fp32 (compact rows)
#define WS_PB     74351104ul   // ushort[NN*512] P1 bf16 (=WS_P+67108864, compact rows)
#define WS_H      141459968ul  // Ax/Hb bf16 packed -> H f32[NN*512] (compact rows)

__device__ __forceinline__ u32 enc_f(float f) {
    u32 b = __float_as_uint(f);
    return (b & 0x80000000u) ? ~b : (b | 0x80000000u);
}
__device__ __forceinline__ float dec_f(u32 m) {
    return (m & 0x80000000u) ? __uint_as_float(m ^ 0x80000000u) : __uint_as_float(~m);
}
__device__ __forceinline__ double wave_sum(double v) {
    #pragma unroll
    for (int off = 32; off > 0; off >>= 1) v += __shfl_down(v, off, 64);
    return v;
}
__device__ __forceinline__ float wave_sum_f(float v) {
    #pragma unroll
    for (int off = 32; off > 0; off >>= 1) v += __shfl_down(v, off, 64);
    return v;
}
__device__ __forceinline__ unsigned short f2bf(float v) {   // RNE f32->bf16
    u32 b = __float_as_uint(v);
    u32 r = b + 0x7FFFu + ((b >> 16) & 1u);
    return (unsigned short)(r >> 16);
}
__device__ __forceinline__ float bf2f(unsigned short h) {
    return __uint_as_float(((u32)h) << 16);
}
__device__ __forceinline__ bf16x8 ld_frag(const unsigned short* p) {
    union { us8 u; bf16x8 b; } t;
    t.u = *(const us8*)p;
    return t.b;
}
// async global->LDS, 16B/lane; lds base must be wave-uniform
__device__ __forceinline__ void dma16(unsigned short* lds, const unsigned short* g) {
    __builtin_amdgcn_global_load_lds((const __attribute__((address_space(1))) u32*)g,
                                     (__attribute__((address_space(3))) u32*)lds, 16, 0, 0);
}

// ---------------- per-node dots + all phase-A init fused ----------------
__global__ void node_dots(const float* __restrict__ x, const float* __restrict__ pw,
                          double* a_d, double* b_d,
                          u32* emax, double* ssum, u32* deg, int* misc,
                          u32* gmaxb, float* gsum, float* gcnt,
                          u64* best, u32* used, int* clus, int* other, float* nsc) {
    int gid = blockIdx.x * blockDim.x + threadIdx.x;
    if (gid < NN) {
        emax[gid] = 0u; ssum[gid] = 0.0; deg[gid] = 0u;
        best[gid] = ~0ull; used[gid] = 0u;
        clus[gid] = gid; other[gid] = -1; nsc[gid] = 1.0f;
    }
    if (gid < 4096) { gmaxb[gid] = 0u; gsum[gid] = 0.0f; }
    if (gid < 64) { misc[gid] = (gid == 1) ? NE : 0; gcnt[gid] = 0.0f; }

    int wave = gid >> 6;
    int lane = threadIdx.x & 63;
    if (wave >= NN) return;
    const float* xr = x + (size_t)wave * FIN;
    double s0 = 0.0, s1 = 0.0;
    for (int f = lane; f < FIN; f += 64) {
        double xv = (double)xr[f];
        s0 += xv * (double)pw[f];
        s1 += xv * (double)pw[FIN + f];
    }
    s0 = wave_sum(s0); s1 = wave_sum(s1);
    if (lane == 0) { a_d[wave] = s0; b_d[wave] = s1; }
}

// ---------------- edge score pipeline ----------------
__global__ void edge_p1(const int* __restrict__ ei, const double* __restrict__ a_d,
                        const double* __restrict__ b_d, const float* __restrict__ pb,
                        double* e_d, u32* emax) {
    int k = blockIdx.x * 256 + threadIdx.x;
    if (k >= NE) return;
    int u = ei[k], v = ei[NE + k];
    double e = a_d[u] + b_d[v] + (double)pb[0];
    e_d[k] = e;
    atomicMax(&emax[v], enc_f((float)e));
}
__global__ void edge_p2(const int* __restrict__ ei, double* e_d,
                        const u32* __restrict__ emax, double* ssum) {
    int k = blockIdx.x * 256 + threadIdx.x;
    if (k >= NE) return;
    int v = ei[NE + k];
    float mf = dec_f(emax[v]);
    double ex = exp(e_d[k] - (double)mf);
    e_d[k] = ex;
    unsafeAtomicAdd(&ssum[v], ex);
}
__global__ void edge_p3(const int* __restrict__ ei, const double* __restrict__ e_d,
                        const double* __restrict__ ssum, float* score, u64* key,
                        int* sel, int* act0, u64* best) {
    int k = blockIdx.x * 256 + threadIdx.x;
    if (k >= NE) return;
    int u = ei[k], v = ei[NE + k];
    float sc = (float)(e_d[k] / ssum[v] + 0.5);
    score[k] = sc;
    u32 m = enc_f(sc);
    u64 kk = ((u64)(m ^ 0xFFFFFFFFu) << 32) | (u32)k;  // low = high score, tie: low idx
    key[k] = kk;
    sel[k] = 0;
    act0[k] = k;
    atomicMin(&best[u], kk);
    atomicMin(&best[v], kk);
}

// ---------------- flattened dominant-edge peeling rounds ----------------
__global__ void mk_sel(const u64* __restrict__ key, const int* __restrict__ ei,
                       const int* __restrict__ act, const int* __restrict__ cntp,
                       int* ncntp, const u64* __restrict__ best,
                       u32* used, int* sel) {
    int cnt = cntp[0];
    int stride = gridDim.x * blockDim.x;
    int gid = blockIdx.x * blockDim.x + threadIdx.x;
    if (gid == 0) ncntp[0] = 0;
    for (int i = gid; i < cnt; i += stride) {
        int e = act[i];
        u64 k = key[e];
        int a = ei[e], b = ei[NE + e];
        if (best[a] == k && best[b] == k) { sel[e] = 1; used[a] = 1u; used[b] = 1u; }
    }
}
__global__ void mk_compact(const int* __restrict__ ei, const int* __restrict__ act,
                           const int* __restrict__ cntp, int* nxt, int* ncntp,
                           u64* best, const u32* __restrict__ used) {
    int cnt = cntp[0];
    int stride = gridDim.x * blockDim.x;
    for (int i = blockIdx.x * blockDim.x + threadIdx.x; i < cnt; i += stride) {
        int e = act[i];
        int a = ei[e], b = ei[NE + e];
        best[a] = ~0ull; best[b] = ~0ull;
        bool live = !(used[a] | used[b]);
        u64 mask = __ballot(live);
        if (mask) {
            int lane = threadIdx.x & 63;
            int leader = __ffsll((unsigned long long)mask) - 1;
            int base = 0;
            if (lane == leader) base = atomicAdd(ncntp, __popcll(mask));
            base = __shfl(base, leader, 64);
            if (live) nxt[base + __popcll(mask & ((1ull << lane) - 1ull))] = e;
        }
    }
}
__global__ void mk_min(const u64* __restrict__ key, const int* __restrict__ ei,
                       const int* __restrict__ act, const int* __restrict__ cntp,
                       u64* best) {
    int cnt = cntp[0];
    int stride = gridDim.x * blockDim.x;
    for (int i = blockIdx.x * blockDim.x + threadIdx.x; i < cnt; i += stride) {
        int e = act[i];
        u64 k = key[e];
        atomicMin(&best[ei[e]], k);
        atomicMin(&best[ei[NE + e]], k);
    }
}
__global__ void __launch_bounds__(1024) match_fin(
        const u64* __restrict__ key, const int* __restrict__ ei,
        int* sel, u64* best, u32* used,
        int* listA, int* listB, const int* __restrict__ cntp) {
    int tid = threadIdx.x;
    int cnt = cntp[0];
    int* cur = listA; int* nxt = listB;
    __shared__ int s_n;
    for (int round = 0; round < 4096 && cnt > 0; ++round) {
        for (int i = tid; i < cnt; i += 1024) {
            int e = cur[i]; u64 k = key[e];
            atomicMin(&best[ei[e]], k);
            atomicMin(&best[ei[NE + e]], k);
        }
        __syncthreads();
        for (int i = tid; i < cnt; i += 1024) {
            int e = cur[i]; u64 k = key[e];
            int a = ei[e], b = ei[NE + e];
            if (best[a] == k && best[b] == k) { sel[e] = 1; used[a] = 1u; used[b] = 1u; }
        }
        if (tid == 0) s_n = 0;
        __syncthreads();
        for (int i = tid; i < cnt; i += 1024) {
            int e = cur[i];
            int a = ei[e], b = ei[NE + e];
            best[a] = ~0ull; best[b] = ~0ull;
            if (!(used[a] | used[b])) {
                int idx = atomicAdd(&s_n, 1);
                nxt[idx] = e;
            }
        }
        __syncthreads();
        cnt = s_n;
        int* t = cur; cur = nxt; nxt = t;
        __syncthreads();
    }
}

// apply_sel + ht init + cin zero (grid = NE/256; KEY dead here)
__global__ void apply_sel(const int* __restrict__ ei, const int* __restrict__ sel,
                          const float* __restrict__ score,
                          int* cluster, int* other, float* nscore,
                          u32* ht, u32* cin) {
    int e = blockIdx.x * 256 + threadIdx.x;
    ht[e << 1] = 0xFFFFFFFFu;
    ht[(e << 1) + 1] = 0xFFFFFFFFu;
    if (e < NN) cin[e] = 0u;
    if (sel[e] != 1) return;
    int u = ei[e], v = ei[NE + e];
    int rep = min(u, v);
    cluster[u] = rep; cluster[v] = rep;
    if (u != v) other[rep] = u + v - rep;
    nscore[rep] = score[e];
}

// ---------------- coarse graph: dedup (cu,cv) pairs via hash set ----------------
__global__ void coarse_build(const int* __restrict__ ei, const int* __restrict__ cluster,
                             u32* ht, int* misc, int* ce_u, int* ce_v, u32* deg,
                             u32* cin) {
    int e = blockIdx.x * 256 + threadIdx.x;
    if (e >= NE) return;
    int cu = cluster[ei[e]], cv = cluster[ei[NE + e]];
    if (cu == cv) return;
    u32 k = (u32)cu * 32768u + (u32)cv;
    u32 h = ((k * 2654435761u) >> 12) & HTM;
    while (true) {
        u32 old = atomicCAS(&ht[h], 0xFFFFFFFFu, k);
        if (old == 0xFFFFFFFFu) {
            int idx = atomicAdd(&misc[0], 1);
            ce_u[idx] = cu; ce_v[idx] = cv;
            atomicAdd(&deg[cu], 1u);
            atomicAdd(&cin[cv], 1u);
            break;
        }
        if (old == k) break;
        h = (h + 1) & HTM;
    }
}

// ---------------- multi-block CSR/compaction scan (3 kernels) ----------------
// pass 1: per-256-elem block sums of cin and valid; FUSED with old dis_kernel
// (identical 128x256 shape, shares the clus load): dis, racc zero, gcnt ballot.
__global__ void __launch_bounds__(256) scan_part(const u32* __restrict__ cin,
                                                 const int* __restrict__ clus,
                                                 int* __restrict__ bsum,
                                                 const u32* __restrict__ deg, float* dis,
                                                 float* racc1, float* racc2,
                                                 const int* __restrict__ batch,
                                                 float* gcnt) {
    int t = threadIdx.x;
    int i = blockIdx.x * 256 + t;
    int cl = clus[i];
    // ---- dis + readout-scratch zero + gcnt (was dis_kernel) ----
    u32 d = deg[i];
    dis[i] = d ? (float)(1.0 / sqrt((double)d)) : 0.0f;
    if (i < 4096) racc1[i] = 0.0f;
    if (i < 2048) racc2[i] = 0.0f;
    bool val = (cl == i);
    int bt = batch[i];
    int lane = t & 63;
    #pragma unroll
    for (int g = 0; g < 8; ++g) {
        u64 m = __ballot(val && bt == g);
        if (m && lane == (__ffsll((unsigned long long)m) - 1))
            unsafeAtomicAdd(&gcnt[g], (float)__popcll(m));
    }
    // ---- block sums of cin and valid ----
    int vc = (int)cin[i];
    int vv = val ? 1 : 0;
    #pragma unroll
    for (int off = 32; off > 0; off >>= 1) {
        vc += __shfl_down(vc, off, 64);
        vv += __shfl_down(vv, off, 64);
    }
    __shared__ int sc[4], sv[4];
    if ((t & 63) == 0) { sc[t >> 6] = vc; sv[t >> 6] = vv; }
    __syncthreads();
    if (t == 0) {
        bsum[blockIdx.x] = sc[0] + sc[1] + sc[2] + sc[3];
        bsum[128 + blockIdx.x] = sv[0] + sv[1] + sv[2] + sv[3];
    }
}
// pass 2: exclusive scan of the 128 block sums (both arrays); misc[4] = total valid
__global__ void __launch_bounds__(128) scan_mid(const int* __restrict__ bsum,
                                                int* __restrict__ boff, int* misc) {
    __shared__ int s[256];
    int t = threadIdx.x;
    int v0 = bsum[t], v1 = bsum[128 + t];
    s[t] = v0; s[128 + t] = v1;
    __syncthreads();
    for (int d = 1; d < 128; d <<= 1) {
        int a = (t >= d) ? s[t - d] : 0;
        int b = (t >= d) ? s[128 + t - d] : 0;
        __syncthreads();
        if (t >= d) { s[t] += a; s[128 + t] += b; }
        __syncthreads();
    }
    boff[t] = s[t] - v0;            // exclusive
    boff[128 + t] = s[128 + t] - v1;
    if (t == 127) misc[4] = s[255];
}
// pass 3: intra-block exclusive scan (packed (cin<<9)|valid; per-block valid sum
// <= 256 < 512 so the 9-bit field never overflows) + block offset + final writes
__global__ void __launch_bounds__(256) scan_fin(const u32* __restrict__ cin,
                                                const int* __restrict__ clus,
                                                const int* __restrict__ boff,
                                                int* off, int* cur, int* cidx, int* perm) {
    __shared__ int s[256];
    int t = threadIdx.x;
    int i = blockIdx.x * 256 + t;
    int vc = (int)cin[i];
    int vv = (clus[i] == i) ? 1 : 0;
    int p = (vc << 9) | vv;
    s[t] = p;
    __syncthreads();
    for (int d = 1; d < 256; d <<= 1) {
        int a = (t >= d) ? s[t - d] : 0;
        __syncthreads();
        if (t >= d) s[t] += a;
        __syncthreads();
    }
    int ex = s[t] - p;   // exclusive packed prefix
    int o = boff[blockIdx.x] + (ex >> 9);
    off[i] = o; cur[i] = o;
    int c = boff[128 + blockIdx.x] + (ex & 511);
    cidx[i] = c;
    if (vv) perm[c] = i;
}

// csr_a stores COMPACT source row indices (cidx available: scan runs first)
__global__ void csr_scatter(const int* __restrict__ ce_u, const int* __restrict__ ce_v,
                            const float* __restrict__ dis, const int* __restrict__ misc,
                            int* cur, int* csr_a, float* csr_c,
                            const int* __restrict__ cidx) {
    int e = blockIdx.x * 256 + threadIdx.x;
    if (e >= misc[0]) return;
    int a = ce_u[e], b = ce_v[e];
    int pos = atomicAdd(&cur[b], 1);
    csr_a[pos] = cidx[a];
    csr_c[pos] = -dis[a] * dis[b];
}

// ---- packed fragment index: row r, col k -> ushort offset ----
__device__ __forceinline__ size_t pk_idx(int r, int k, int KT) {
    return ((((size_t)(r >> 4) * KT + (k >> 5)) << 6) + (((k >> 3) & 3) << 4) + (r & 15)) << 3;
}

// ---------------- fused: packed Ax gather (COMPACT rows, LDS-staged coalesced) ----------------
__global__ void __launch_bounds__(256) conv_all(
        const float* __restrict__ x, const int* __restrict__ perm,
        const int* __restrict__ misc,
        const int* __restrict__ other, const float* __restrict__ nsc,
        unsigned short* __restrict__ Abf, float* __restrict__ pxl,
        const float* __restrict__ B10, const float* __restrict__ B11,
        unsigned short* __restrict__ Bp1,
        const float* __restrict__ B20, const float* __restrict__ B21,
        unsigned short* __restrict__ Bp2) {
    int bid = blockIdx.x;
    int t = threadIdx.x;
    if (bid < 2048) {   // A-tile gather via coalesced row staging in LDS
        __shared__ unsigned short S[16][1032];   // +8 ushort pad: 2-way max bank alias
        __shared__ int Srow[16], So[16];
        __shared__ float Ss[16];
        int cnt = misc[4];
        int tile = bid;
        if ((tile << 4) >= ((cnt + 127) & ~127)) return;  // beyond padded M': unread
        if (t < 16) {
            int ci = (tile << 4) + t;
            bool val = ci < cnt;
            int row = val ? perm[ci] : -1;
            Srow[t] = row;
            So[t] = val ? other[row] : -1;
            Ss[t] = val ? nsc[row] : 0.0f;
        }
        __syncthreads();
        if (t < 16) {   // pxl (col 1024), 16 scattered scalar loads — tiny
            int row = Srow[t];
            float v = 0.0f;
            if (row >= 0) {
                int o = So[t];
                v = x[(size_t)row * FIN + 1024];
                if (o >= 0) v += x[(size_t)o * FIN + 1024];
                v *= Ss[t];
            }
            pxl[(tile << 4) + t] = v;
        }
        // stage 16 rows: lane t reads cols t, t+256, t+512, t+768 — fully coalesced
        for (int r = 0; r < 16; ++r) {
            int row = Srow[r];          // wave-uniform
            int o = So[r];
            float s = Ss[r];
            if (row >= 0) {
                const float* xr = x + (size_t)row * FIN;
                const float* xo = x + (size_t)(o >= 0 ? o : row) * FIN;
                #pragma unroll
                for (int k = 0; k < 4; ++k) {
                    int c = (k << 8) + t;
                    float v = xr[c];
                    if (o >= 0) v += xo[c];
                    S[r][c] = f2bf(v * s);
                }
            } else {
                #pragma unroll
                for (int k = 0; k < 4; ++k) S[r][(k << 8) + t] = 0;
            }
        }
        __syncthreads();
        // pack: 16B LDS reads -> 16B global stores
        int wave = t >> 6, lane = t & 63;
        int l16 = lane & 15, quad = lane >> 4;
        #pragma unroll
        for (int kt0 = 0; kt0 < 8; ++kt0) {
            int kt = (kt0 << 2) + wave;
            int c0 = (kt << 5) + (quad << 3);
            us8 v = *(const us8*)&S[l16][c0];
            *(us8*)&Abf[((((size_t)tile << 5) + kt) << 9) + ((size_t)lane << 3)] = v;
        }
    } else if (bid < 2560) {   // L1 weight transpose, KT=32
        int j = bid - 2048;
        int n = ((j & 3) << 8) + t;
        int k0 = (j >> 2) << 3;
        unsigned short h[8];
        #pragma unroll
        for (int jj = 0; jj < 8; ++jj) {
            int k = k0 + jj;
            float v = (n < 512) ? B10[(size_t)k * 512 + n] : B11[(size_t)k * 512 + (n - 512)];
            h[jj] = f2bf(v);
        }
        *(us8*)&Bp1[pk_idx(n, k0, 32)] = *(const us8*)h;
    } else {                   // L2 weight transpose, KT=16
        int j = bid - 2560;
        int n = ((j & 3) << 8) + t;
        int k0 = (j >> 2) << 3;
        unsigned short h[8];
        #pragma unroll
        for (int jj = 0; jj < 8; ++jj) {
            int k = k0 + jj;
            float v = (n < 512) ? B20[(size_t)k * 512 + n] : B21[(size_t)k * 512 + (n - 512)];
            h[jj] = f2bf(v);
        }
        *(us8*)&Bp2[pk_idx(n, k0, 16)] = *(const us8*)h;
    }
}

// ---------------- packed-fragment bf16 MFMA GEMM with LDS DMA double-buffer ----------------
// BM=64 x BN=128 tiles (finer M): ~2256 active blocks halve per-block time so the
// 1024-slot co-residency quantization costs 1.5T instead of 2T. 12 LDS fragments
// (4 A + 8 B) = 24 KB double-buffered; 3 dma16/wave; each wave computes 32x64 via
// acc[4][2] (transposed D^T form, direct float4/us4 stores).
template <bool R1>
__global__ void __launch_bounds__(256, 4) gemm_pk(
        const unsigned short* __restrict__ Ap, const unsigned short* __restrict__ Bp,
        float* __restrict__ P, unsigned short* __restrict__ Pb, int KT,
        const float* __restrict__ pxl, const float* __restrict__ w0,
        const float* __restrict__ w1, const int* __restrict__ msc) {
    __shared__ unsigned short L[2][6144];
    int tid = threadIdx.x;
    int bid = blockIdx.x;
    int bn = (bid & 7) << 7;
    int bm = (bid >> 3) << 6;                    // BM=64; dead blocks = contiguous tail
    if (bm >= ((msc[4] + 127) & ~127)) return;   // zero-row block: output never read
    int wave = tid >> 6, lane = tid & 63, quad = lane >> 4, l16 = lane & 15;
    int moff = (wave >> 1) << 5, noff = (wave & 1) << 6;   // wave: 32 M x 64 N
    f32x4 acc[4][2];   // [ni][mi] — transposed-output fragments
    #pragma unroll
    for (int i = 0; i < 4; ++i)
        #pragma unroll
        for (int j = 0; j < 2; ++j) acc[i][j] = (f32x4){0.f, 0.f, 0.f, 0.f};

    const unsigned short* src[3];
    unsigned short* dst[3];
    #pragma unroll
    for (int q = 0; q < 3; ++q) {
        int f = wave * 3 + q;                    // 12 frags: 0..3 = A, 4..11 = B
        int tg = (f < 4) ? ((bm >> 4) + f) : ((bn >> 4) + (f - 4));
        src[q] = ((f < 4) ? Ap : Bp) + (((size_t)tg * KT) << 9) + ((size_t)lane << 3);
        dst[q] = &L[0][(size_t)f << 9];
    }
    const unsigned short* ra = &L[0][(size_t)((wave >> 1) << 1) << 9];      // A frags
    const unsigned short* rb = &L[0][(size_t)(4 + ((wave & 1) << 2)) << 9]; // B frags

    #pragma unroll
    for (int q = 0; q < 3; ++q) dma16(dst[q], src[q]);
    __syncthreads();

    int cur = 0;
    for (int kt = 0; kt < KT; ++kt) {
        if (kt + 1 < KT) {
            int nb = (cur ^ 1) * 6144;
            size_t go = ((size_t)(kt + 1)) << 9;
            #pragma unroll
            for (int q = 0; q < 3; ++q) dma16(dst[q] + nb, src[q] + go);
        }
        const unsigned short* la = ra + cur * 6144;
        const unsigned short* lb = rb + cur * 6144;
        bf16x8 af[2], bf[4];
        #pragma unroll
        for (int i = 0; i < 2; ++i) af[i] = ld_frag(la + ((size_t)i << 9) + (lane << 3));
        #pragma unroll
        for (int i = 0; i < 4; ++i) bf[i] = ld_frag(lb + ((size_t)i << 9) + (lane << 3));
        #pragma unroll
        for (int ni = 0; ni < 4; ++ni)
            #pragma unroll
            for (int mi = 0; mi < 2; ++mi)
                acc[ni][mi] = __builtin_amdgcn_mfma_f32_16x16x32_bf16(bf[ni], af[mi], acc[ni][mi], 0, 0, 0);
        __syncthreads();
        cur ^= 1;
    }
    // ---- epilogue: D^T: n = bn+noff+ni*16+quad*4+r2, m = bm+moff+mi*16+l16 ----
    #pragma unroll
    for (int mi = 0; mi < 2; ++mi) {
        int m = bm + moff + (mi << 4) + l16;
        float pm = 0.0f;
        if (R1) pm = pxl[m];
        #pragma unroll
        for (int ni = 0; ni < 4; ++ni) {
            int n0 = bn + noff + (ni << 4) + (quad << 2);
            float v0 = acc[ni][mi][0], v1 = acc[ni][mi][1];
            float v2 = acc[ni][mi][2], v3 = acc[ni][mi][3];
            if (bn < 512) {
                if (R1) {
                    float4 wv = *(const float4*)&w0[524288 + n0];
                    v0 += pm * wv.x; v1 += pm * wv.y; v2 += pm * wv.z; v3 += pm * wv.w;
                }
                *(float4*)&P[(size_t)m * 512 + n0] = make_float4(v0, v1, v2, v3);
            } else {
                if (R1) {
                    float4 wv = *(const float4*)&w1[524288 + n0 - 512];
                    v0 += pm * wv.x; v1 += pm * wv.y; v2 += pm * wv.z; v3 += pm * wv.w;
                }
                unsigned short h[4] = {f2bf(v0), f2bf(v1), f2bf(v2), f2bf(v3)};
                *(us4*)&Pb[(size_t)m * 512 + (n0 - 512)] = *(const us4*)h;
            }
        }
    }
}

// ---------------- fused gather + BN + ReLU: one wave per COMPACT destination row ----------------
template <bool BF16OUT>
__global__ void __launch_bounds__(256) cheb_fuse(
        const float* __restrict__ P, const unsigned short* __restrict__ Pb,
        const int* __restrict__ off,
        const int* __restrict__ csr_a, const float* __restrict__ csr_c,
        const int* __restrict__ misc, const float* __restrict__ bias,
        const float* __restrict__ bn, float* __restrict__ Hf,
        unsigned short* __restrict__ Hb, const int* __restrict__ perm) {
    int b = (blockIdx.x * 256 + threadIdx.x) >> 6;
    int lane = threadIdx.x & 63;
    if (b >= misc[4]) return;
    int r = perm[b];
    int s = off[r];
    int e = (r < NN - 1) ? off[r + 1] : misc[0];
    int c0 = lane << 3;
    float a0[4], a1[4];
    {
        float4 t0 = *(const float4*)&P[(size_t)b * 512 + c0];
        float4 t1 = *(const float4*)&P[(size_t)b * 512 + c0 + 4];
        a0[0] = t0.x; a0[1] = t0.y; a0[2] = t0.z; a0[3] = t0.w;
        a1[0] = t1.x; a1[1] = t1.y; a1[2] = t1.z; a1[3] = t1.w;
    }
    for (int j = s; j < e; ++j) {
        int a = csr_a[j];          // already a compact row index
        float cf = csr_c[j];
        us8 raw = *(const us8*)&Pb[(size_t)a * 512 + c0];
        a0[0] = fmaf(cf, bf2f(raw[0]), a0[0]); a0[1] = fmaf(cf, bf2f(raw[1]), a0[1]);
        a0[2] = fmaf(cf, bf2f(raw[2]), a0[2]); a0[3] = fmaf(cf, bf2f(raw[3]), a0[3]);
        a1[0] = fmaf(cf, bf2f(raw[4]), a1[0]); a1[1] = fmaf(cf, bf2f(raw[5]), a1[1]);
        a1[2] = fmaf(cf, bf2f(raw[6]), a1[2]); a1[3] = fmaf(cf, bf2f(raw[7]), a1[3]);
    }
    float o[8];
    #pragma unroll
    for (int i = 0; i < 8; ++i) {
        int j = c0 + i;
        float acc = (i < 4) ? a0[i] : a1[i - 4];
        float ga = bn[j], be = bn[512 + j], mn = bn[1024 + j], vr = bn[1536 + j];
        float sc = (float)(1.0 / sqrt((double)vr + 1e-5));
        float v = (acc + bias[j] - mn) * sc * ga + be;
        o[i] = v > 0.0f ? v : 0.0f;
    }
    if (BF16OUT) {
        unsigned short h[8];
        #pragma unroll
        for (int i = 0; i < 8; ++i) h[i] = f2bf(o[i]);
        *(us8*)&Hb[pk_idx(b, c0, 16)] = *(const us8*)h;   // packed for layer-2 GEMM
    } else {
        *(float4*)&Hf[(size_t)b * 512 + c0] = make_float4(o[0], o[1], o[2], o[3]);
        *(float4*)&Hf[(size_t)b * 512 + c0 + 4] = make_float4(o[4], o[5], o[6], o[7]);
    }
}

// ---------------- global max+mean pool over valid nodes per graph ----------------
__global__ void __launch_bounds__(256) pool_kernel(
        const float* __restrict__ H, const int* __restrict__ cluster,
        const int* __restrict__ batch, u32* gmaxb, float* gsum,
        const int* __restrict__ cidx) {
    int t = threadIdx.x;
    int n0 = blockIdx.x * 16;
    float m0 = 0.0f, m1 = 0.0f, s0 = 0.0f, s1 = 0.0f;
    int cur = batch[n0];
    for (int i = 0; i < 16; ++i) {
        int n = n0 + i;
        int bt = batch[n];
        if (bt != cur) {
            atomicMax(&gmaxb[cur * 512 + t], __float_as_uint(m0));
            atomicMax(&gmaxb[cur * 512 + t + 256], __float_as_uint(m1));
            unsafeAtomicAdd(&gsum[cur * 512 + t], s0);
            unsafeAtomicAdd(&gsum[cur * 512 + t + 256], s1);
            m0 = m1 = s0 = s1 = 0.0f; cur = bt;
        }
        if (cluster[n] == n) {
            size_t ci = (size_t)cidx[n];
            float h0 = H[ci * 512 + t];
            float h1 = H[ci * 512 + t + 256];
            m0 = fmaxf(m0, h0); m1 = fmaxf(m1, h1);
            s0 += h0; s1 += h1;
        }
    }
    atomicMax(&gmaxb[cur * 512 + t], __float_as_uint(m0));
    atomicMax(&gmaxb[cur * 512 + t + 256], __float_as_uint(m1));
    unsafeAtomicAdd(&gsum[cur * 512 + t], s0);
    unsafeAtomicAdd(&gsum[cur * 512 + t + 256], s1);
}

// ---------------- parallel readout MLP (3 kernels) ----------------
__global__ void __launch_bounds__(512) ro1(
        const u32* __restrict__ gmaxb, const float* __restrict__ gsum,
        const float* __restrict__ gcnt, const float* __restrict__ l1w,
        float* __restrict__ racc1) {
    int o = threadIdx.x;
    int k0 = blockIdx.x << 4;
    float acc[8] = {0, 0, 0, 0, 0, 0, 0, 0};
    float inv[8];
    #pragma unroll
    for (int b = 0; b < 8; ++b) inv[b] = 1.0f / fmaxf(gcnt[b], 1.0f);
    for (int kk = 0; kk < 16; ++kk) {
        int k = k0 + kk;
        float w = l1w[(size_t)k * 512 + o];
        #pragma unroll
        for (int b = 0; b < 8; ++b) {
            float g = (k < 512) ? __uint_as_float(gmaxb[b * 512 + k])
                                : gsum[b * 512 + (k - 512)] * inv[b];
            acc[b] = fmaf(g, w, acc[b]);
        }
    }
    #pragma unroll
    for (int b = 0; b < 8; ++b) unsafeAtomicAdd(&racc1[b * 512 + o], acc[b]);
}
// ro3: layer-2 partials with ro2's BN inlined (recomputed per k-slice)
__global__ void __launch_bounds__(256) ro3(
        const float* __restrict__ racc1, const float* __restrict__ l1b,
        const float* __restrict__ bn3, const float* __restrict__ l2w,
        float* __restrict__ racc2) {
    int o = threadIdx.x;
    int k0 = blockIdx.x << 4;
    float acc[8] = {0, 0, 0, 0, 0, 0, 0, 0};
    for (int kk = 0; kk < 16; ++kk) {
        int k = k0 + kk;
        float ga = bn3[k], be = bn3[512 + k], mn = bn3[1024 + k], vr = bn3[1536 + k];
        float sc = (float)(1.0 / sqrt((double)vr + 1e-5));
        float bi = l1b[k];
        float w = l2w[(size_t)k * 256 + o];
        #pragma unroll
        for (int b = 0; b < 8; ++b) {
            float g1 = (racc1[b * 512 + k] + bi - mn) * sc * ga + be;
            g1 = g1 > 0.0f ? g1 : 0.0f;
            acc[b] = fmaf(g1, w, acc[b]);
        }
    }
    #pragma unroll
    for (int b = 0; b < 8; ++b) unsafeAtomicAdd(&racc2[b * 256 + o], acc[b]);
}
// ro4: BN+relu into G2 (feature out), then WAVE-PARALLEL 8x4 final matmul
// (was: 8 serial threads x 1024-deep FMA chains — a single-block serial tail).
// 4 waves x 8 (b,c) pairs; lane ln sums k = ln+64i (4 FMAs) + shuffle reduce.
__global__ void __launch_bounds__(256) ro4(
        const float* __restrict__ racc2, const float* __restrict__ l2b,
        const float* __restrict__ bn4, const float* __restrict__ l3w,
        const float* __restrict__ l3b, float* __restrict__ out) {
    __shared__ float G2[8 * 256];
    __shared__ float W3[1024];
    __shared__ float R[32];
    int o = threadIdx.x;
    #pragma unroll
    for (int i = 0; i < 4; ++i) W3[o + (i << 8)] = l3w[o + (i << 8)];
    {
        float ga = bn4[o], be = bn4[256 + o], mn = bn4[512 + o], vr = bn4[768 + o];
        float sc = (float)(1.0 / sqrt((double)vr + 1e-5));
        float bi = l2b[o];
        #pragma unroll
        for (int b = 0; b < 8; ++b) {
            float v = (racc2[b * 256 + o] + bi - mn) * sc * ga + be;
            v = v > 0.0f ? v : 0.0f;
            G2[b * 256 + o] = v;
            out[32 + b * 256 + o] = v;
        }
    }
    __syncthreads();
    int wv = o >> 6, ln = o & 63;
    #pragma unroll
    for (int q = 0; q < 8; ++q) {
        int p = (wv << 3) + q;       // 0..31
        int b = p >> 2, c = p & 3;
        float a = 0.0f;
        #pragma unroll
        for (int i = 0; i < 4; ++i) {
            int k = ln + (i << 6);
            a = fmaf(G2[b * 256 + k], W3[k * 4 + c], a);
        }
        a = wave_sum_f(a);
        if (ln == 0) R[p] = a + l3b[c];
    }
    __syncthreads();
    if (o < 8) {
        int b = o;
        float r[4];
        #pragma unroll
        for (int c = 0; c < 4; ++c) {
            float acc = R[b * 4 + c];
            r[c] = acc > 0.0f ? acc : 0.0f;
        }
        float mx = fmaxf(fmaxf(r[0], r[1]), fmaxf(r[2], r[3]));
        float s = 0.0f;
        #pragma unroll
        for (int c = 0; c < 4; ++c) s += expf(r[c] - mx);
        float lse = mx + logf(s);
        #pragma unroll
        for (int c = 0; c < 4; ++c) out[b * 4 + c] = r[c] - lse;
    }
}

extern "C" void kernel_launch(void* const* d_in, const int* in_sizes, int n_in,
                              void* d_out, int out_size, void* d_ws, size_t ws_size,
                              hipStream_t stream) {
    const float* x      = (const float*)d_in[0];
    const int*   ei     = (const int*)d_in[1];
    const int*   batch  = (const int*)d_in[2];
    const float* pool_w = (const float*)d_in[3];
    const float* pool_b = (const float*)d_in[4];
    const float* c1_w0  = (const float*)d_in[5];
    const float* c1_w1  = (const float*)d_in[6];
    const float* c1_b   = (const float*)d_in[7];
    const float* c2_w0  = (const float*)d_in[8];
    const float* c2_w1  = (const float*)d_in[9];
    const float* c2_b   = (const float*)d_in[10];
    const float* bn1    = (const float*)d_in[11];
    const float* bn2    = (const float*)d_in[12];
    const float* bn3    = (const float*)d_in[13];
    const float* bn4    = (const float*)d_in[14];
    const float* l1w    = (const float*)d_in[15];
    const float* l1b    = (const float*)d_in[16];
    const float* l2w    = (const float*)d_in[17];
    const float* l2b    = (const float*)d_in[18];
    const float* l3w    = (const float*)d_in[19];
    const float* l3b    = (const float*)d_in[20];
    float* out = (float*)d_out;
    char* ws = (char*)d_ws;

    double* a_d   = (double*)(ws + WS_A_D);
    double* b_d   = (double*)(ws + WS_B_D);
    u32*    emax  = (u32*)(ws + WS_EMAX);
    double* ssum  = (double*)(ws + WS_SSUM);
    double* exd   = (double*)(ws + WS_EXD);
    u32*    cin   = (u32*)(ws + WS_CIN);
    int*    cidxp = (int*)(ws + WS_CIDX);
    int*    permp = (int*)(ws + WS_PERM);
    int*    bsum  = (int*)(ws + WS_BSUM);
    int*    boffp = (int*)(ws + WS_BOFF);
    u64*    key   = (u64*)(ws + WS_KEY);
    u64*    best  = (u64*)(ws + WS_BEST);
    u32*    used  = (u32*)(ws + WS_USED);
    int*    curp  = (int*)(ws + WS_CUR);
    int*    act0  = (int*)(ws + WS_ACT0);
    int*    act1  = (int*)(ws + WS_ACT1);
    unsigned short* bthi = (unsigned short*)(ws + WS_BTHI);
    unsigned short* bt2  = (unsigned short*)(ws + WS_BT2);
    float*  pxl   = (float*)(ws + WS_PXL);
    u32*    ht    = (u32*)(ws + WS_HT);
    float*  racc1 = (float*)(ws + WS_RACC1);
    float*  racc2 = (float*)(ws + WS_RACC2);
    float*  score = (float*)(ws + WS_SCORE);
    int*    csr_a = (int*)(ws + WS_CSRA);
    int*    sel   = (int*)(ws + WS_SEL);
    float*  csr_c = (float*)(ws + WS_CSRC);
    int*    clus  = (int*)(ws + WS_CLUST);
    int*    other = (int*)(ws + WS_OTHER);
    float*  nsc   = (float*)(ws + WS_NSC);
    int*    ce_u  = (int*)(ws + WS_CEU);
    int*    ce_v  = (int*)(ws + WS_CEV);
    u32*    deg   = (u32*)(ws + WS_DEG);
    int*    off   = (int*)(ws + WS_OFF);
    float*  dis   = (float*)(ws + WS_DIS);
    int*    misc  = (int*)(ws + WS_MISC);
    u32*    gmaxb = (u32*)(ws + WS_GMAX);
    float*  gsum  = (float*)(ws + WS_GSUM);
    float*  gcnt  = (float*)(ws + WS_GCNT);
    float*  P     = (float*)(ws + WS_P);
    unsigned short* Pb = (unsigned short*)(ws + WS_PB);
    unsigned short* ax = (unsigned short*)(ws + WS_H);   // packed Ax bf16 (gemm1 A)
    unsigned short* hb = (unsigned short*)(ws + WS_H);   // packed Hb bf16 (gemm2 A)
    float*  H     = (float*)(ws + WS_H);                 // final H fp32

    // ---- phase A: scores, matching, coarse graph ----
    node_dots<<<NN / 4, 256, 0, stream>>>(x, pool_w, a_d, b_d,
                                          emax, ssum, deg, misc, gmaxb, gsum, gcnt,
                                          best, used, clus, other, nsc);
    edge_p1<<<NE / 256, 256, 0, stream>>>(ei, a_d, b_d, pool_b, exd, emax);
    edge_p2<<<NE / 256, 256, 0, stream>>>(ei, exd, emax, ssum);
    edge_p3<<<NE / 256, 256, 0, stream>>>(ei, exd, ssum, score, key, sel, act0, best);

    {
        static const int gr[5] = {512, 512, 256, 128, 64};
        int* acts[2] = {act0, act1};
        for (int r = 0; r < 4; ++r) {
            int c = r & 1, n = 1 - c;
            mk_sel<<<gr[r], 256, 0, stream>>>(key, ei, acts[c], &misc[1 + c],
                                              &misc[1 + n], best, used, sel);
            mk_compact<<<gr[r], 256, 0, stream>>>(ei, acts[c], &misc[1 + c],
                                                  acts[n], &misc[1 + n], best, used);
            mk_min<<<gr[r + 1], 256, 0, stream>>>(key, ei, acts[n], &misc[1 + n], best);
        }
        match_fin<<<1, 1024, 0, stream>>>(key, ei, sel, best, used,
                                          act0, act1, &misc[1]);
    }

    apply_sel<<<NE / 256, 256, 0, stream>>>(ei, sel, score, clus, other, nsc, ht, cin);
    coarse_build<<<NE / 256, 256, 0, stream>>>(ei, clus, ht, misc, ce_u, ce_v, deg, cin);
    scan_part<<<128, 256, 0, stream>>>(cin, clus, bsum, deg, dis, racc1, racc2, batch,
                                       gcnt);
    scan_mid<<<1, 128, 0, stream>>>(bsum, boffp, misc);
    scan_fin<<<128, 256, 0, stream>>>(cin, clus, boffp, off, curp, cidxp, permp);
    csr_scatter<<<NE / 256, 256, 0, stream>>>(ce_u, ce_v, dis, misc, curp, csr_a, csr_c,
                                              cidxp);

    // ---- phase B: ChebConv layers on COMPACT rows (misc[4] ~ 0.55*NN survive) ----
    conv_all<<<2816, 256, 0, stream>>>(x, permp, misc, other, nsc, ax, pxl,
                                       c1_w0, c1_w1, bthi, c2_w0, c2_w1, bt2);
    gemm_pk<true><<<4096, 256, 0, stream>>>(ax, bthi, P, Pb, 32, pxl, c1_w0, c1_w1, misc);
    cheb_fuse<true><<<NN / 4, 256, 0, stream>>>(P, Pb, off, csr_a, csr_c, misc, c1_b, bn1,
                                                nullptr, hb, permp);

    gemm_pk<false><<<4096, 256, 0, stream>>>(hb, bt2, P, Pb, 16, nullptr, nullptr, nullptr,
                                             misc);
    cheb_fuse<false><<<NN / 4, 256, 0, stream>>>(P, Pb, off, csr_a, csr_c, misc, c2_b, bn2,
                                                 H, nullptr, permp);

    pool_kernel<<<NN / 16, 256, 0, stream>>>(H, clus, batch, gmaxb, gsum, cidxp);

    // ---- parallel readout ----
    ro1<<<64, 512, 0, stream>>>(gmaxb, gsum, gcnt, l1w, racc1);
    ro3<<<32, 256, 0, stream>>>(racc1, l1b, bn3, l2w, racc2);
    ro4<<<1, 256, 0, stream>>>(racc2, l2b, bn4, l3w, l3b, out);
}